// Round 6
// baseline (215.173 us; speedup 1.0000x reference)
//
#include <hip/hip_runtime.h>
#include <stdint.h>

typedef unsigned short u16;
typedef unsigned int u32;
typedef __bf16 bf16x8 __attribute__((ext_vector_type(8)));
typedef float f32x4 __attribute__((ext_vector_type(4)));

#define NH 12
#define HD 64
#define SEQ 512
#define BATCH 16
#define HID 768
#define SCALE_Q 0.03608439182435161f  // 768^-0.5

__device__ __forceinline__ u16 f2bf(float f) {
    u32 u = __builtin_bit_cast(u32, f);
    u32 r = (u + 0x7FFFu + ((u >> 16) & 1u)) >> 16;
    return (u16)r;
}
__device__ __forceinline__ float bf2f(u16 h) {
    return __builtin_bit_cast(float, (u32)h << 16);
}

// async global -> LDS, 16B per lane; lds dest = wave-uniform base + lane*16
__device__ __forceinline__ void gl2lds16(const u16* g, u16* lds_base) {
    __builtin_amdgcn_global_load_lds(
        (const __attribute__((address_space(1))) u32*)g,
        (__attribute__((address_space(3))) u32*)lds_base, 16, 0, 0);
}

// ---------------- fused fp32 -> bf16 convert: [x | wq | wk | wv | wo] contiguous ----------------
#define NXB 6144   // NX/1024
#define NWB 576    // NW/1024
__global__ void cvt_all(const float* __restrict__ x,
                        const float* __restrict__ w0, const float* __restrict__ w1,
                        const float* __restrict__ w2, const float* __restrict__ w3,
                        u16* __restrict__ dst) {
    int b = blockIdx.x;
    const float* s; int sb;
    if (b < NXB) { s = x; sb = 0; }
    else if (b < NXB + NWB) { s = w0; sb = NXB; }
    else if (b < NXB + 2 * NWB) { s = w1; sb = NXB + NWB; }
    else if (b < NXB + 3 * NWB) { s = w2; sb = NXB + 2 * NWB; }
    else { s = w3; sb = NXB + 3 * NWB; }
    int li = (b - sb) * 1024 + threadIdx.x * 4;
    float4 v = *(const float4*)(s + li);
    ushort4 o;
    o.x = f2bf(v.x); o.y = f2bf(v.y); o.z = f2bf(v.z); o.w = f2bf(v.w);
    *(ushort4*)(dst + (size_t)b * 1024 + threadIdx.x * 4) = o;
}

// ---------------- E transpose + convert: ebt[b][k][q] = bf16(E[b][q][k]) ----------------
// 64x64 f32 tile per block via LDS [64][66] (66 u16 rows -> odd bank stride, conflict-light).
__global__ void cvt_tr_e(const float* __restrict__ eb, u16* __restrict__ ebt) {
    __shared__ u16 t[64][66];
    const int bb = blockIdx.z;
    const int qt0 = blockIdx.x * 64;   // q tile origin (row of E)
    const int kt0 = blockIdx.y * 64;   // k tile origin (col of E)
    const int tid = threadIdx.x;
    const int r = tid >> 2;            // 0..63
    const int c4 = (tid & 3) * 16;     // 0,16,32,48

    const float* src = eb + ((size_t)bb * SEQ + qt0 + r) * SEQ + kt0 + c4;
#pragma unroll
    for (int j = 0; j < 4; j++) {
        float4 v = *(const float4*)(src + j * 4);
        t[r][c4 + j * 4 + 0] = f2bf(v.x);
        t[r][c4 + j * 4 + 1] = f2bf(v.y);
        t[r][c4 + j * 4 + 2] = f2bf(v.z);
        t[r][c4 + j * 4 + 3] = f2bf(v.w);
    }
    __syncthreads();
    // out row = k-local r; cols = q-local c4..c4+15
    u16* dst = ebt + ((size_t)bb * SEQ + kt0 + r) * SEQ + qt0 + c4;
#pragma unroll
    for (int j = 0; j < 4; j++) {
        ushort4 o;
        o.x = t[c4 + j * 4 + 0][r];
        o.y = t[c4 + j * 4 + 1][r];
        o.z = t[c4 + j * 4 + 2][r];
        o.w = t[c4 + j * 4 + 3][r];
        *(ushort4*)(dst + j * 4) = o;
    }
}

// ---------------- NT GEMM mainloop: 3-buffer ring, prefetch distance 2, counted vmcnt ----------------
// (R1 verbatim — measured 54-58 us for gemm_qkv; at the m97-structure ceiling for this shape)
__device__ __forceinline__ void stage_gemm(
    const u16* __restrict__ Ag, const u16* __restrict__ Bg, int k0,
    u16* As, u16* Bs, int r0, int q0, int r1, int q1, int w)
{
    gl2lds16(Ag + (size_t)r0 * HID + k0 + q0, As + w * 512);
    gl2lds16(Ag + (size_t)r1 * HID + k0 + q1, As + 2048 + w * 512);
    gl2lds16(Bg + (size_t)r0 * HID + k0 + q0, Bs + w * 512);
    gl2lds16(Bg + (size_t)r1 * HID + k0 + q1, Bs + 2048 + w * 512);
}

__device__ __forceinline__ void gemm_mainloop(
    const u16* __restrict__ Ag, const u16* __restrict__ Bg,
    u16 (*As)[128 * 32], u16 (*Bs)[128 * 32], f32x4 (&acc)[4][4])
{
    const int tid = threadIdx.x;
    const int l = tid & 63, w = tid >> 6;
    const int wm = w & 1, wn = w >> 1;
    const int lr = l & 15, lg = l >> 4;

    const int c0 = tid, c1 = tid + 256;
    const int r0 = c0 >> 2, q0 = (((c0 & 3) ^ ((r0 >> 1) & 3)) * 8);
    const int r1 = c1 >> 2, q1 = (((c1 & 3) ^ ((r1 >> 1) & 3)) * 8);

    const int sA = (lg ^ ((lr >> 1) & 3)) * 8;

    stage_gemm(Ag, Bg, 0, As[0], Bs[0], r0, q0, r1, q1, w);
    stage_gemm(Ag, Bg, 32, As[1], Bs[1], r0, q0, r1, q1, w);

    int cur = 0;
    for (int i = 0; i < 24; i++) {
        if (i < 23)
            asm volatile("s_waitcnt vmcnt(4) lgkmcnt(0)" ::: "memory");
        else
            asm volatile("s_waitcnt vmcnt(0) lgkmcnt(0)" ::: "memory");
        __builtin_amdgcn_s_barrier();
        __builtin_amdgcn_sched_barrier(0);

        int nxt = cur + 2; if (nxt >= 3) nxt -= 3;
        if (i < 22)
            stage_gemm(Ag, Bg, (i + 2) * 32, As[nxt], Bs[nxt], r0, q0, r1, q1, w);

        bf16x8 af[4], bfr[4];
#pragma unroll
        for (int mi = 0; mi < 4; mi++)
            af[mi] = *(const bf16x8*)(As[cur] + (wm * 64 + mi * 16 + lr) * 32 + sA);
#pragma unroll
        for (int ni = 0; ni < 4; ni++)
            bfr[ni] = *(const bf16x8*)(Bs[cur] + (wn * 64 + ni * 16 + lr) * 32 + sA);
#pragma unroll
        for (int mi = 0; mi < 4; mi++)
#pragma unroll
            for (int ni = 0; ni < 4; ni++)
                acc[mi][ni] = __builtin_amdgcn_mfma_f32_16x16x32_bf16(af[mi], bfr[ni], acc[mi][ni], 0, 0, 0);

        cur += 1; if (cur >= 3) cur -= 3;
    }
}

// ---------------- fused QKV GEMM (R1 linear decode: mt fastest => A panels XCD-local) ----------------
__global__ __launch_bounds__(256, 3) void gemm_qkv(
    const u16* __restrict__ xb, const u16* __restrict__ wq,
    const u16* __restrict__ wk, const u16* __restrict__ wv,
    const float* __restrict__ bv,
    u16* __restrict__ qtb, u16* __restrict__ kb, u16* __restrict__ vtb)
{
    __shared__ __align__(16) u16 As[3][128 * 32];
    __shared__ __align__(16) u16 Bs[3][128 * 32];
    const int tid = threadIdx.x;
    const int l = tid & 63, w = tid >> 6;
    const int wm = w & 1, wn = w >> 1;
    const int lr = l & 15, lg = l >> 4;
    const int mt = blockIdx.x, nt = blockIdx.y, z = blockIdx.z;

    const u16* Bw = (z == 0) ? wq : (z == 1) ? wk : wv;
    const u16* Ag = xb + (size_t)(mt * 128) * HID;
    const u16* Bg = Bw + (size_t)(nt * 128) * HID;

    f32x4 acc[4][4] = {};
    gemm_mainloop(Ag, Bg, As, Bs, acc);

    const float sc = (z == 0) ? SCALE_Q : 1.0f;
#pragma unroll
    for (int mi = 0; mi < 4; mi++) {
#pragma unroll
        for (int ni = 0; ni < 4; ni++) {
            const int jg = nt * 128 + wn * 64 + ni * 16 + lr;
            const int h = jg >> 6, d = jg & 63;
            const int i0 = mt * 128 + wm * 64 + mi * 16 + lg * 4;
            const int b = i0 >> 9, n0 = i0 & 511;
            if (z == 1) {  // K: [b,h,m,d]
#pragma unroll
                for (int r2 = 0; r2 < 4; r2++)
                    kb[((size_t)(b * NH + h) * SEQ + n0 + r2) * HD + d] = f2bf(acc[mi][ni][r2]);
            } else {       // Q/V: [b,h,d,n] packed along n
                float bb = (z == 2) ? bv[jg] : 0.0f;
                ushort4 pk;
                pk.x = f2bf(fmaf(acc[mi][ni][0], sc, bb));
                pk.y = f2bf(fmaf(acc[mi][ni][1], sc, bb));
                pk.z = f2bf(fmaf(acc[mi][ni][2], sc, bb));
                pk.w = f2bf(fmaf(acc[mi][ni][3], sc, bb));
                u16* O = (z == 0) ? qtb : vtb;
                *(ushort4*)(O + ((size_t)(b * NH + h) * HD + d) * SEQ + n0) = pk;
            }
        }
    }
}

// ---------------- output GEMM: fp32 out + bias (R2 XCD-chunked remap) ----------------
__global__ __launch_bounds__(256, 3) void gemm_out(
    const u16* __restrict__ A, const u16* __restrict__ wo,
    const float* __restrict__ bo, float* __restrict__ Cout)
{
    __shared__ __align__(16) u16 As[3][128 * 32];
    __shared__ __align__(16) u16 Bs[3][128 * 32];
    const int tid = threadIdx.x;
    const int l = tid & 63, w = tid >> 6;
    const int wm = w & 1, wn = w >> 1;
    const int lr = l & 15, lg = l >> 4;

    const int L = blockIdx.x;
    const int xcd = L & 7, s = L >> 3;
    const int nt = s >> 3;
    const int mt = xcd * 8 + (s & 7);

    const u16* Ag = A + (size_t)(mt * 128) * HID;
    const u16* Bg = wo + (size_t)(nt * 128) * HID;

    f32x4 acc[4][4] = {};
    gemm_mainloop(Ag, Bg, As, Bs, acc);

#pragma unroll
    for (int mi = 0; mi < 4; mi++) {
#pragma unroll
        for (int ni = 0; ni < 4; ni++) {
            const int jg = nt * 128 + wn * 64 + ni * 16 + lr;
            float bb = bo[jg];
#pragma unroll
            for (int r2 = 0; r2 < 4; r2++) {
                int ig = mt * 128 + wm * 64 + mi * 16 + lg * 4 + r2;
                Cout[(size_t)ig * HID + jg] = acc[mi][ni][r2] + bb;
            }
        }
    }
}

// ---------------- fused flash attention (R2-exact structure + E^T vector bias) ----------------
__device__ __forceinline__ void stage_kv(
    const u16* __restrict__ Kg, const u16* __restrict__ Vg, int mt0,
    u16* Ksb, u16* Vsb, int kr0, int kc0, int kr1, int kc1, int w)
{
    gl2lds16(Kg + (size_t)(mt0 + kr0) * HD + kc0 * 8, Ksb + w * 512);
    gl2lds16(Kg + (size_t)(mt0 + kr1) * HD + kc1 * 8, Ksb + 2048 + w * 512);
    gl2lds16(Vg + (size_t)kr0 * SEQ + mt0 + kc0 * 8, Vsb + w * 512);
    gl2lds16(Vg + (size_t)kr1 * SEQ + mt0 + kc1 * 8, Vsb + 2048 + w * 512);
}

__global__ __launch_bounds__(256, 4) void attn_kernel(
    const u16* __restrict__ qtb, const u16* __restrict__ kb, const u16* __restrict__ vtb,
    const u16* __restrict__ ebt, u16* __restrict__ ob)
{
    __shared__ __align__(16) u16 Ks[2][64 * 64];
    __shared__ __align__(16) u16 Vs[2][64 * 64];
    __shared__ __align__(16) u16 Ps[4][16 * 64];

    const int tid = threadIdx.x;
    const int l = tid & 63, w = tid >> 6;
    const int lr = l & 15, lg = l >> 4;

    // XCD-aware decode (R2): 2 batches per XCD; h outer, qt inner ->
    // K/V(b,h) (256KB, x8 reuse) and bias rows (x12 reuse) stay in own-XCD L2.
    const int L = blockIdx.x;
    const int xcd = L & 7, s = L >> 3;            // s in [0,192)
    const int b = xcd * 2 + (s / 96);
    const int s2 = s % 96;
    const int h = s2 >> 3, qt = s2 & 7;

    const int bh = b * NH + h;
    const int qrow0 = qt * 64 + w * 16;

    const u16* Kg = kb + (size_t)bh * SEQ * HD;
    const u16* Vg = vtb + (size_t)bh * HD * SEQ;
    // E^T [b][k][q]: lane's bias row k = mt0 + mi*16 + lr; 4 q-values contiguous
    const u16* Egt = ebt + (size_t)b * SEQ * SEQ;

    // staging chunk assignment (swizzled): p = row*8 + (c ^ (row&7))
    const int p0 = tid, p1 = tid + 256;
    const int kr0 = p0 >> 3, kc0 = (p0 & 7) ^ (kr0 & 7);
    const int kr1 = p1 >> 3, kc1 = (p1 & 7) ^ (kr1 & 7);

    stage_kv(Kg, Vg, 0, Ks[0], Vs[0], kr0, kc0, kr1, kc1, w);

    // Q fragments (A-layout) gathered from transposed Q [b,h,d,n]
    const u16* Qg = qtb + (size_t)bh * HD * SEQ + qrow0 + lr;
    bf16x8 qf0, qf1;
#pragma unroll
    for (int j = 0; j < 8; j++) {
        qf0[j] = __builtin_bit_cast(__bf16, Qg[(size_t)(lg * 8 + j) * SEQ]);
        qf1[j] = __builtin_bit_cast(__bf16, Qg[(size_t)(lg * 8 + j + 32) * SEQ]);
    }

    bf16x8 ones;
#pragma unroll
    for (int j = 0; j < 8; j++) ones[j] = __builtin_bit_cast(__bf16, (u16)0x3F80);

    f32x4 oacc[4] = {};
    f32x4 lacc = {};
    float amax[4] = {0.f, 0.f, 0.f, 0.f};

    for (int t = 0; t < 8; t++) {
        const int cur = t & 1;
        const int mt0 = t * 64;
        __syncthreads();  // drains tile-t loads; prev tile's reads done

        // bias loads FIRST (vmcnt-ordered before the prefetch below): 4 x ushort4
        // bl4[mi] component r == E[b][qrow0+lg*4+r][mt0+mi*16+lr]
        ushort4 bl4[4];
#pragma unroll
        for (int mi = 0; mi < 4; mi++)
            bl4[mi] = *(const ushort4*)(Egt + (size_t)(mt0 + mi * 16 + lr) * SEQ + qrow0 + lg * 4);

        if (t < 7)
            stage_kv(Kg, Vg, mt0 + 64, Ks[cur ^ 1], Vs[cur ^ 1], kr0, kc0, kr1, kc1, w);

        // S = (Q*scale) K^T + bias (bias as MFMA C-init); P = exp(S), no max
        float sm[4][4];
#pragma unroll
        for (int mi = 0; mi < 4; mi++) {
            const int row = mi * 16 + lr;
            bf16x8 kf0 = *(const bf16x8*)(Ks[cur] + row * 64 + ((lg ^ (row & 7)) * 8));
            bf16x8 kf1 = *(const bf16x8*)(Ks[cur] + row * 64 + (((4 + lg) ^ (row & 7)) * 8));
            f32x4 s;
            s[0] = bf2f(bl4[mi].x); s[1] = bf2f(bl4[mi].y);
            s[2] = bf2f(bl4[mi].z); s[3] = bf2f(bl4[mi].w);
            s = __builtin_amdgcn_mfma_f32_16x16x32_bf16(qf0, kf0, s, 0, 0, 0);
            s = __builtin_amdgcn_mfma_f32_16x16x32_bf16(qf1, kf1, s, 0, 0, 0);
#pragma unroll
            for (int r = 0; r < 4; r++) {
                float sv = s[r];
                amax[r] = fmaxf(amax[r], fabsf(sv));
                sm[mi][r] = __expf(sv);
            }
        }

        // P: C-layout -> per-wave swizzled LDS -> A-layout
        u16* Pw = Ps[w];
#pragma unroll
        for (int mi = 0; mi < 4; mi++)
#pragma unroll
            for (int r = 0; r < 4; r++) {
                const int q = lg * 4 + r;
                const int chunk = mi * 2 + (lr >> 3);
                Pw[q * 64 + ((chunk ^ (q & 7)) * 8) + (lr & 7)] = f2bf(sm[mi][r]);
            }

#pragma unroll
        for (int ks = 0; ks < 2; ks++) {
            bf16x8 pf = *(const bf16x8*)(Pw + lr * 64 + (((ks * 4 + lg) ^ (lr & 7)) * 8));
#pragma unroll
            for (int di = 0; di < 4; di++) {
                const int row = di * 16 + lr;
                bf16x8 vf = *(const bf16x8*)(Vs[cur] + row * 64 + (((ks * 4 + lg) ^ (row & 7)) * 8));
                oacc[di] = __builtin_amdgcn_mfma_f32_16x16x32_bf16(pf, vf, oacc[di], 0, 0, 0);
            }
            lacc = __builtin_amdgcn_mfma_f32_16x16x32_bf16(pf, ones, lacc, 0, 0, 0);
        }
    }

#pragma unroll
    for (int r = 0; r < 4; r++) {
        float am = amax[r];
        am = fmaxf(am, __shfl_xor(am, 1));
        am = fmaxf(am, __shfl_xor(am, 2));
        am = fmaxf(am, __shfl_xor(am, 4));
        am = fmaxf(am, __shfl_xor(am, 8));
        float inv = (am > 0.f) ? (1.0f / lacc[r]) : 0.0f;  // all-zero row -> 0 (ref: NaN->0)
        int n = qrow0 + lg * 4 + r;
        u16* orow = ob + ((size_t)b * SEQ + n) * HID + h * HD;
#pragma unroll
        for (int di = 0; di < 4; di++)
            orow[di * 16 + lr] = f2bf(oacc[di][r] * inv);
    }
}

// ---------------- launch ----------------
extern "C" void kernel_launch(void* const* d_in, const int* in_sizes, int n_in,
                              void* d_out, int out_size, void* d_ws, size_t ws_size,
                              hipStream_t stream) {
    (void)in_sizes; (void)n_in; (void)out_size; (void)ws_size;
    const float* x  = (const float*)d_in[0];
    const float* eb = (const float*)d_in[1];
    const float* Wq = (const float*)d_in[2];
    const float* Wk = (const float*)d_in[3];
    const float* Wv = (const float*)d_in[4];
    const float* bv = (const float*)d_in[5];
    const float* Wo = (const float*)d_in[6];
    const float* bo = (const float*)d_in[7];
    float* out = (float*)d_out;

    const int NX = BATCH * SEQ * HID;   // 6291456
    const int NW = HID * HID;           // 589824
    const int NE = BATCH * SEQ * SEQ;   // 4194304
    u16* ws   = (u16*)d_ws;
    u16* xb   = ws;                 // contiguous cvt region: [x | wq | wk | wv | wo]
    u16* wqb  = xb + NX;
    u16* wkb  = wqb + NW;
    u16* wvb  = wkb + NW;
    u16* wob  = wvb + NW;
    u16* ebt  = wob + NW;           // E^T [b][k][q] (bf16)
    u16* qtb  = ebt + NE;
    u16* kb   = qtb + NX;
    u16* vtb  = kb + NX;
    u16* obuf = vtb + NX;

    cvt_all<<<NXB + 4 * NWB, 256, 0, stream>>>(x, Wq, Wk, Wv, Wo, ws);

    cvt_tr_e<<<dim3(8, 8, 16), 256, 0, stream>>>(eb, ebt);

    gemm_qkv<<<dim3(64, 6, 3), 256, 0, stream>>>(xb, wqb, wkb, wvb, bv, qtb, kb, vtb);

    attn_kernel<<<1536, 256, 0, stream>>>(qtb, kb, vtb, ebt, obuf);

    gemm_out<<<384, 256, 0, stream>>>(obuf, wob, bo, out);
}

// Round 7
// 200.343 us; speedup vs baseline: 1.0740x; 1.0740x over previous
//
#include <hip/hip_runtime.h>
#include <stdint.h>

typedef unsigned short u16;
typedef unsigned int u32;
typedef __bf16 bf16x8 __attribute__((ext_vector_type(8)));
typedef float f32x4 __attribute__((ext_vector_type(4)));

#define NH 12
#define HD 64
#define SEQ 512
#define BATCH 16
#define HID 768
#define SCALE_Q 0.03608439182435161f  // 768^-0.5

__device__ __forceinline__ u16 f2bf(float f) {
    u32 u = __builtin_bit_cast(u32, f);
    u32 r = (u + 0x7FFFu + ((u >> 16) & 1u)) >> 16;
    return (u16)r;
}
__device__ __forceinline__ float bf2f(u16 h) {
    return __builtin_bit_cast(float, (u32)h << 16);
}

// async global -> LDS, 16B per lane; lds dest = wave-uniform base + lane*16
__device__ __forceinline__ void gl2lds16(const u16* g, u16* lds_base) {
    __builtin_amdgcn_global_load_lds(
        (const __attribute__((address_space(1))) u32*)g,
        (__attribute__((address_space(3))) u32*)lds_base, 16, 0, 0);
}

// ---------------- fused fp32 -> bf16 convert: [x | wq | wk | wv | wo] contiguous ----------------
// (eb is NOT converted: attention reads the f32 bias directly — saves 24 MB of cvt traffic)
#define NXB 6144   // NX/1024
#define NWB 576    // NW/1024
__global__ void cvt_all(const float* __restrict__ x,
                        const float* __restrict__ w0, const float* __restrict__ w1,
                        const float* __restrict__ w2, const float* __restrict__ w3,
                        u16* __restrict__ dst) {
    int b = blockIdx.x;
    const float* s; int sb;
    if (b < NXB) { s = x; sb = 0; }
    else if (b < NXB + NWB) { s = w0; sb = NXB; }
    else if (b < NXB + 2 * NWB) { s = w1; sb = NXB + NWB; }
    else if (b < NXB + 3 * NWB) { s = w2; sb = NXB + 2 * NWB; }
    else { s = w3; sb = NXB + 3 * NWB; }
    int li = (b - sb) * 1024 + threadIdx.x * 4;
    float4 v = *(const float4*)(s + li);
    ushort4 o;
    o.x = f2bf(v.x); o.y = f2bf(v.y); o.z = f2bf(v.z); o.w = f2bf(v.w);
    *(ushort4*)(dst + (size_t)b * 1024 + threadIdx.x * 4) = o;
}

// ---------------- NT GEMM mainloop: 3-buffer ring, prefetch distance 2, counted vmcnt ----------------
// (R1 verbatim — measured 54-58 us for gemm_qkv; at the m97-structure ceiling for this shape)
__device__ __forceinline__ void stage_gemm(
    const u16* __restrict__ Ag, const u16* __restrict__ Bg, int k0,
    u16* As, u16* Bs, int r0, int q0, int r1, int q1, int w)
{
    gl2lds16(Ag + (size_t)r0 * HID + k0 + q0, As + w * 512);
    gl2lds16(Ag + (size_t)r1 * HID + k0 + q1, As + 2048 + w * 512);
    gl2lds16(Bg + (size_t)r0 * HID + k0 + q0, Bs + w * 512);
    gl2lds16(Bg + (size_t)r1 * HID + k0 + q1, Bs + 2048 + w * 512);
}

__device__ __forceinline__ void gemm_mainloop(
    const u16* __restrict__ Ag, const u16* __restrict__ Bg,
    u16 (*As)[128 * 32], u16 (*Bs)[128 * 32], f32x4 (&acc)[4][4])
{
    const int tid = threadIdx.x;
    const int l = tid & 63, w = tid >> 6;
    const int wm = w & 1, wn = w >> 1;
    const int lr = l & 15, lg = l >> 4;

    const int c0 = tid, c1 = tid + 256;
    const int r0 = c0 >> 2, q0 = (((c0 & 3) ^ ((r0 >> 1) & 3)) * 8);
    const int r1 = c1 >> 2, q1 = (((c1 & 3) ^ ((r1 >> 1) & 3)) * 8);

    const int sA = (lg ^ ((lr >> 1) & 3)) * 8;

    stage_gemm(Ag, Bg, 0, As[0], Bs[0], r0, q0, r1, q1, w);
    stage_gemm(Ag, Bg, 32, As[1], Bs[1], r0, q0, r1, q1, w);

    int cur = 0;
    for (int i = 0; i < 24; i++) {
        if (i < 23)
            asm volatile("s_waitcnt vmcnt(4) lgkmcnt(0)" ::: "memory");
        else
            asm volatile("s_waitcnt vmcnt(0) lgkmcnt(0)" ::: "memory");
        __builtin_amdgcn_s_barrier();
        __builtin_amdgcn_sched_barrier(0);

        int nxt = cur + 2; if (nxt >= 3) nxt -= 3;
        if (i < 22)
            stage_gemm(Ag, Bg, (i + 2) * 32, As[nxt], Bs[nxt], r0, q0, r1, q1, w);

        bf16x8 af[4], bfr[4];
#pragma unroll
        for (int mi = 0; mi < 4; mi++)
            af[mi] = *(const bf16x8*)(As[cur] + (wm * 64 + mi * 16 + lr) * 32 + sA);
#pragma unroll
        for (int ni = 0; ni < 4; ni++)
            bfr[ni] = *(const bf16x8*)(Bs[cur] + (wn * 64 + ni * 16 + lr) * 32 + sA);
#pragma unroll
        for (int mi = 0; mi < 4; mi++)
#pragma unroll
            for (int ni = 0; ni < 4; ni++)
                acc[mi][ni] = __builtin_amdgcn_mfma_f32_16x16x32_bf16(af[mi], bfr[ni], acc[mi][ni], 0, 0, 0);

        cur += 1; if (cur >= 3) cur -= 3;
    }
}

// ---------------- fused QKV GEMM (R1 linear decode: mt fastest => A panels XCD-local) ----------------
__global__ __launch_bounds__(256, 3) void gemm_qkv(
    const u16* __restrict__ xb, const u16* __restrict__ wq,
    const u16* __restrict__ wk, const u16* __restrict__ wv,
    const float* __restrict__ bv,
    u16* __restrict__ qtb, u16* __restrict__ kb, u16* __restrict__ vtb)
{
    __shared__ __align__(16) u16 As[3][128 * 32];
    __shared__ __align__(16) u16 Bs[3][128 * 32];
    const int tid = threadIdx.x;
    const int l = tid & 63, w = tid >> 6;
    const int wm = w & 1, wn = w >> 1;
    const int lr = l & 15, lg = l >> 4;
    const int mt = blockIdx.x, nt = blockIdx.y, z = blockIdx.z;

    const u16* Bw = (z == 0) ? wq : (z == 1) ? wk : wv;
    const u16* Ag = xb + (size_t)(mt * 128) * HID;
    const u16* Bg = Bw + (size_t)(nt * 128) * HID;

    f32x4 acc[4][4] = {};
    gemm_mainloop(Ag, Bg, As, Bs, acc);

    const float sc = (z == 0) ? SCALE_Q : 1.0f;
#pragma unroll
    for (int mi = 0; mi < 4; mi++) {
#pragma unroll
        for (int ni = 0; ni < 4; ni++) {
            const int jg = nt * 128 + wn * 64 + ni * 16 + lr;
            const int h = jg >> 6, d = jg & 63;
            const int i0 = mt * 128 + wm * 64 + mi * 16 + lg * 4;
            const int b = i0 >> 9, n0 = i0 & 511;
            if (z == 1) {  // K: [b,h,m,d]
#pragma unroll
                for (int r2 = 0; r2 < 4; r2++)
                    kb[((size_t)(b * NH + h) * SEQ + n0 + r2) * HD + d] = f2bf(acc[mi][ni][r2]);
            } else {       // Q/V: [b,h,d,n] packed along n
                float bb = (z == 2) ? bv[jg] : 0.0f;
                ushort4 pk;
                pk.x = f2bf(fmaf(acc[mi][ni][0], sc, bb));
                pk.y = f2bf(fmaf(acc[mi][ni][1], sc, bb));
                pk.z = f2bf(fmaf(acc[mi][ni][2], sc, bb));
                pk.w = f2bf(fmaf(acc[mi][ni][3], sc, bb));
                u16* O = (z == 0) ? qtb : vtb;
                *(ushort4*)(O + ((size_t)(b * NH + h) * HD + d) * SEQ + n0) = pk;
            }
        }
    }
}

// ---------------- output GEMM: fp32 out + bias (R2 XCD-chunked remap) ----------------
__global__ __launch_bounds__(256, 3) void gemm_out(
    const u16* __restrict__ A, const u16* __restrict__ wo,
    const float* __restrict__ bo, float* __restrict__ Cout)
{
    __shared__ __align__(16) u16 As[3][128 * 32];
    __shared__ __align__(16) u16 Bs[3][128 * 32];
    const int tid = threadIdx.x;
    const int l = tid & 63, w = tid >> 6;
    const int wm = w & 1, wn = w >> 1;
    const int lr = l & 15, lg = l >> 4;

    const int L = blockIdx.x;
    const int xcd = L & 7, s = L >> 3;
    const int nt = s >> 3;
    const int mt = xcd * 8 + (s & 7);

    const u16* Ag = A + (size_t)(mt * 128) * HID;
    const u16* Bg = wo + (size_t)(nt * 128) * HID;

    f32x4 acc[4][4] = {};
    gemm_mainloop(Ag, Bg, As, Bs, acc);

#pragma unroll
    for (int mi = 0; mi < 4; mi++) {
#pragma unroll
        for (int ni = 0; ni < 4; ni++) {
            const int jg = nt * 128 + wn * 64 + ni * 16 + lr;
            float bb = bo[jg];
#pragma unroll
            for (int r2 = 0; r2 < 4; r2++) {
                int ig = mt * 128 + wm * 64 + mi * 16 + lg * 4 + r2;
                Cout[(size_t)ig * HID + jg] = acc[mi][ni][r2] + bb;
            }
        }
    }
}

// ---------------- fused flash attention (R2-exact structure; bias read as f32) ----------------
__device__ __forceinline__ void stage_kv(
    const u16* __restrict__ Kg, const u16* __restrict__ Vg, int mt0,
    u16* Ksb, u16* Vsb, int kr0, int kc0, int kr1, int kc1, int w)
{
    gl2lds16(Kg + (size_t)(mt0 + kr0) * HD + kc0 * 8, Ksb + w * 512);
    gl2lds16(Kg + (size_t)(mt0 + kr1) * HD + kc1 * 8, Ksb + 2048 + w * 512);
    gl2lds16(Vg + (size_t)kr0 * SEQ + mt0 + kc0 * 8, Vsb + w * 512);
    gl2lds16(Vg + (size_t)kr1 * SEQ + mt0 + kc1 * 8, Vsb + 2048 + w * 512);
}

__global__ __launch_bounds__(256, 4) void attn_kernel(
    const u16* __restrict__ qtb, const u16* __restrict__ kb, const u16* __restrict__ vtb,
    const float* __restrict__ eb, u16* __restrict__ ob)
{
    __shared__ __align__(16) u16 Ks[2][64 * 64];
    __shared__ __align__(16) u16 Vs[2][64 * 64];
    __shared__ __align__(16) u16 Ps[4][16 * 64];

    const int tid = threadIdx.x;
    const int l = tid & 63, w = tid >> 6;
    const int lr = l & 15, lg = l >> 4;

    // XCD-aware decode (R2): 2 batches per XCD; h outer, qt inner ->
    // K/V(b,h) (256KB, x8 reuse) and bias rows (x12 reuse) stay in own-XCD L2.
    const int L = blockIdx.x;
    const int xcd = L & 7, s = L >> 3;            // s in [0,192)
    const int b = xcd * 2 + (s / 96);
    const int s2 = s % 96;
    const int h = s2 >> 3, qt = s2 & 7;

    const int bh = b * NH + h;
    const int qrow0 = qt * 64 + w * 16;

    const u16* Kg = kb + (size_t)bh * SEQ * HD;
    const u16* Vg = vtb + (size_t)bh * HD * SEQ;
    const float* Eg = eb + ((size_t)b * SEQ + qrow0 + lg * 4) * SEQ;

    // staging chunk assignment (swizzled): p = row*8 + (c ^ (row&7))
    const int p0 = tid, p1 = tid + 256;
    const int kr0 = p0 >> 3, kc0 = (p0 & 7) ^ (kr0 & 7);
    const int kr1 = p1 >> 3, kc1 = (p1 & 7) ^ (kr1 & 7);

    stage_kv(Kg, Vg, 0, Ks[0], Vs[0], kr0, kc0, kr1, kc1, w);

    // Q fragments (A-layout) gathered from transposed Q [b,h,d,n]
    const u16* Qg = qtb + (size_t)bh * HD * SEQ + qrow0 + lr;
    bf16x8 qf0, qf1;
#pragma unroll
    for (int j = 0; j < 8; j++) {
        qf0[j] = __builtin_bit_cast(__bf16, Qg[(size_t)(lg * 8 + j) * SEQ]);
        qf1[j] = __builtin_bit_cast(__bf16, Qg[(size_t)(lg * 8 + j + 32) * SEQ]);
    }

    bf16x8 ones;
#pragma unroll
    for (int j = 0; j < 8; j++) ones[j] = __builtin_bit_cast(__bf16, (u16)0x3F80);

    f32x4 oacc[4] = {};
    f32x4 lacc = {};
    float amax[4] = {0.f, 0.f, 0.f, 0.f};

    for (int t = 0; t < 8; t++) {
        const int cur = t & 1;
        const int mt0 = t * 64;
        __syncthreads();  // drains tile-t loads; prev tile's reads done

        // bias loads FIRST (vmcnt-ordered before the prefetch below); f32 direct
        float bl[4][4];
#pragma unroll
        for (int mi = 0; mi < 4; mi++)
#pragma unroll
            for (int r = 0; r < 4; r++)
                bl[mi][r] = Eg[(size_t)r * SEQ + mt0 + mi * 16 + lr];

        if (t < 7)
            stage_kv(Kg, Vg, mt0 + 64, Ks[cur ^ 1], Vs[cur ^ 1], kr0, kc0, kr1, kc1, w);

        // S = (Q*scale) K^T + bias (bias as MFMA C-init); P = exp(S), no max
        float sm[4][4];
#pragma unroll
        for (int mi = 0; mi < 4; mi++) {
            const int row = mi * 16 + lr;
            bf16x8 kf0 = *(const bf16x8*)(Ks[cur] + row * 64 + ((lg ^ (row & 7)) * 8));
            bf16x8 kf1 = *(const bf16x8*)(Ks[cur] + row * 64 + (((4 + lg) ^ (row & 7)) * 8));
            f32x4 s;
#pragma unroll
            for (int r = 0; r < 4; r++) s[r] = bl[mi][r];
            s = __builtin_amdgcn_mfma_f32_16x16x32_bf16(qf0, kf0, s, 0, 0, 0);
            s = __builtin_amdgcn_mfma_f32_16x16x32_bf16(qf1, kf1, s, 0, 0, 0);
#pragma unroll
            for (int r = 0; r < 4; r++) {
                float sv = s[r];
                amax[r] = fmaxf(amax[r], fabsf(sv));
                sm[mi][r] = __expf(sv);
            }
        }

        // P: C-layout -> per-wave swizzled LDS -> A-layout
        u16* Pw = Ps[w];
#pragma unroll
        for (int mi = 0; mi < 4; mi++)
#pragma unroll
            for (int r = 0; r < 4; r++) {
                const int q = lg * 4 + r;
                const int chunk = mi * 2 + (lr >> 3);
                Pw[q * 64 + ((chunk ^ (q & 7)) * 8) + (lr & 7)] = f2bf(sm[mi][r]);
            }

#pragma unroll
        for (int ks = 0; ks < 2; ks++) {
            bf16x8 pf = *(const bf16x8*)(Pw + lr * 64 + (((ks * 4 + lg) ^ (lr & 7)) * 8));
#pragma unroll
            for (int di = 0; di < 4; di++) {
                const int row = di * 16 + lr;
                bf16x8 vf = *(const bf16x8*)(Vs[cur] + row * 64 + (((ks * 4 + lg) ^ (row & 7)) * 8));
                oacc[di] = __builtin_amdgcn_mfma_f32_16x16x32_bf16(pf, vf, oacc[di], 0, 0, 0);
            }
            lacc = __builtin_amdgcn_mfma_f32_16x16x32_bf16(pf, ones, lacc, 0, 0, 0);
        }
    }

#pragma unroll
    for (int r = 0; r < 4; r++) {
        float am = amax[r];
        am = fmaxf(am, __shfl_xor(am, 1));
        am = fmaxf(am, __shfl_xor(am, 2));
        am = fmaxf(am, __shfl_xor(am, 4));
        am = fmaxf(am, __shfl_xor(am, 8));
        float inv = (am > 0.f) ? (1.0f / lacc[r]) : 0.0f;  // all-zero row -> 0 (ref: NaN->0)
        int n = qrow0 + lg * 4 + r;
        u16* orow = ob + ((size_t)b * SEQ + n) * HID + h * HD;
#pragma unroll
        for (int di = 0; di < 4; di++)
            orow[di * 16 + lr] = f2bf(oacc[di][r] * inv);
    }
}

// ---------------- launch ----------------
extern "C" void kernel_launch(void* const* d_in, const int* in_sizes, int n_in,
                              void* d_out, int out_size, void* d_ws, size_t ws_size,
                              hipStream_t stream) {
    (void)in_sizes; (void)n_in; (void)out_size; (void)ws_size;
    const float* x  = (const float*)d_in[0];
    const float* eb = (const float*)d_in[1];
    const float* Wq = (const float*)d_in[2];
    const float* Wk = (const float*)d_in[3];
    const float* Wv = (const float*)d_in[4];
    const float* bv = (const float*)d_in[5];
    const float* Wo = (const float*)d_in[6];
    const float* bo = (const float*)d_in[7];
    float* out = (float*)d_out;

    const int NX = BATCH * SEQ * HID;   // 6291456
    const int NW = HID * HID;           // 589824
    u16* ws   = (u16*)d_ws;
    u16* xb   = ws;                 // contiguous cvt region: [x | wq | wk | wv | wo]
    u16* wqb  = xb + NX;
    u16* wkb  = wqb + NW;
    u16* wvb  = wkb + NW;
    u16* wob  = wvb + NW;
    u16* qtb  = wob + NW;
    u16* kb   = qtb + NX;
    u16* vtb  = kb + NX;
    u16* obuf = vtb + NX;

    cvt_all<<<NXB + 4 * NWB, 256, 0, stream>>>(x, Wq, Wk, Wv, Wo, ws);

    gemm_qkv<<<dim3(64, 6, 3), 256, 0, stream>>>(xb, wqb, wkb, wvb, bv, qtb, kb, vtb);

    attn_kernel<<<1536, 256, 0, stream>>>(qtb, kb, vtb, eb, obuf);

    gemm_out<<<384, 256, 0, stream>>>(obuf, wob, bo, out);
}

// Round 8
// 200.266 us; speedup vs baseline: 1.0744x; 1.0004x over previous
//
#include <hip/hip_runtime.h>
#include <stdint.h>

typedef unsigned short u16;
typedef unsigned int u32;
typedef __bf16 bf16x8 __attribute__((ext_vector_type(8)));
typedef float f32x4 __attribute__((ext_vector_type(4)));

#define NH 12
#define HD 64
#define SEQ 512
#define BATCH 16
#define HID 768
#define SCALE_Q 0.03608439182435161f  // 768^-0.5

__device__ __forceinline__ u16 f2bf(float f) {
    u32 u = __builtin_bit_cast(u32, f);
    u32 r = (u + 0x7FFFu + ((u >> 16) & 1u)) >> 16;
    return (u16)r;
}
__device__ __forceinline__ float bf2f(u16 h) {
    return __builtin_bit_cast(float, (u32)h << 16);
}

// async global -> LDS, 16B per lane; lds dest = wave-uniform base + lane*16
__device__ __forceinline__ void gl2lds16(const u16* g, u16* lds_base) {
    __builtin_amdgcn_global_load_lds(
        (const __attribute__((address_space(1))) u32*)g,
        (__attribute__((address_space(3))) u32*)lds_base, 16, 0, 0);
}

// ---------------- fused fp32 -> bf16 convert (all 6 tensors, one launch) ----------------
// eb IS converted (bf16 bias): halves attn bias traffic and keeps L3 pressure low for qkv.
#define NXB 6144   // NX/1024
#define NEB 4096   // NE/1024
#define NWB 576    // NW/1024
__global__ void cvt_all(const float* __restrict__ x, const float* __restrict__ eb,
                        const float* __restrict__ w0, const float* __restrict__ w1,
                        const float* __restrict__ w2, const float* __restrict__ w3,
                        u16* __restrict__ dst) {
    int b = blockIdx.x;
    const float* s; int sb;
    if (b < NXB) { s = x; sb = 0; }
    else if (b < NXB + NEB) { s = eb; sb = NXB; }
    else if (b < NXB + NEB + NWB) { s = w0; sb = NXB + NEB; }
    else if (b < NXB + NEB + 2 * NWB) { s = w1; sb = NXB + NEB + NWB; }
    else if (b < NXB + NEB + 3 * NWB) { s = w2; sb = NXB + NEB + 2 * NWB; }
    else { s = w3; sb = NXB + NEB + 3 * NWB; }
    int li = (b - sb) * 1024 + threadIdx.x * 4;
    float4 v = *(const float4*)(s + li);
    ushort4 o;
    o.x = f2bf(v.x); o.y = f2bf(v.y); o.z = f2bf(v.z); o.w = f2bf(v.w);
    *(ushort4*)(dst + (size_t)b * 1024 + threadIdx.x * 4) = o;
}

// ---------------- NT GEMM mainloop: 3-buffer ring, prefetch distance 2, counted vmcnt ----------------
// (R1 verbatim — measured 54-58 us for gemm_qkv; at the m97-structure ceiling for this shape)
__device__ __forceinline__ void stage_gemm(
    const u16* __restrict__ Ag, const u16* __restrict__ Bg, int k0,
    u16* As, u16* Bs, int r0, int q0, int r1, int q1, int w)
{
    gl2lds16(Ag + (size_t)r0 * HID + k0 + q0, As + w * 512);
    gl2lds16(Ag + (size_t)r1 * HID + k0 + q1, As + 2048 + w * 512);
    gl2lds16(Bg + (size_t)r0 * HID + k0 + q0, Bs + w * 512);
    gl2lds16(Bg + (size_t)r1 * HID + k0 + q1, Bs + 2048 + w * 512);
}

__device__ __forceinline__ void gemm_mainloop(
    const u16* __restrict__ Ag, const u16* __restrict__ Bg,
    u16 (*As)[128 * 32], u16 (*Bs)[128 * 32], f32x4 (&acc)[4][4])
{
    const int tid = threadIdx.x;
    const int l = tid & 63, w = tid >> 6;
    const int wm = w & 1, wn = w >> 1;
    const int lr = l & 15, lg = l >> 4;

    const int c0 = tid, c1 = tid + 256;
    const int r0 = c0 >> 2, q0 = (((c0 & 3) ^ ((r0 >> 1) & 3)) * 8);
    const int r1 = c1 >> 2, q1 = (((c1 & 3) ^ ((r1 >> 1) & 3)) * 8);

    const int sA = (lg ^ ((lr >> 1) & 3)) * 8;

    stage_gemm(Ag, Bg, 0, As[0], Bs[0], r0, q0, r1, q1, w);
    stage_gemm(Ag, Bg, 32, As[1], Bs[1], r0, q0, r1, q1, w);

    int cur = 0;
    for (int i = 0; i < 24; i++) {
        if (i < 23)
            asm volatile("s_waitcnt vmcnt(4) lgkmcnt(0)" ::: "memory");
        else
            asm volatile("s_waitcnt vmcnt(0) lgkmcnt(0)" ::: "memory");
        __builtin_amdgcn_s_barrier();
        __builtin_amdgcn_sched_barrier(0);

        int nxt = cur + 2; if (nxt >= 3) nxt -= 3;
        if (i < 22)
            stage_gemm(Ag, Bg, (i + 2) * 32, As[nxt], Bs[nxt], r0, q0, r1, q1, w);

        bf16x8 af[4], bfr[4];
#pragma unroll
        for (int mi = 0; mi < 4; mi++)
            af[mi] = *(const bf16x8*)(As[cur] + (wm * 64 + mi * 16 + lr) * 32 + sA);
#pragma unroll
        for (int ni = 0; ni < 4; ni++)
            bfr[ni] = *(const bf16x8*)(Bs[cur] + (wn * 64 + ni * 16 + lr) * 32 + sA);
#pragma unroll
        for (int mi = 0; mi < 4; mi++)
#pragma unroll
            for (int ni = 0; ni < 4; ni++)
                acc[mi][ni] = __builtin_amdgcn_mfma_f32_16x16x32_bf16(af[mi], bfr[ni], acc[mi][ni], 0, 0, 0);

        cur += 1; if (cur >= 3) cur -= 3;
    }
}

// ---------------- fused QKV GEMM (R1 linear decode: mt fastest => A panels XCD-local) ----------------
__global__ __launch_bounds__(256, 3) void gemm_qkv(
    const u16* __restrict__ xb, const u16* __restrict__ wq,
    const u16* __restrict__ wk, const u16* __restrict__ wv,
    const float* __restrict__ bv,
    u16* __restrict__ qtb, u16* __restrict__ kb, u16* __restrict__ vtb)
{
    __shared__ __align__(16) u16 As[3][128 * 32];
    __shared__ __align__(16) u16 Bs[3][128 * 32];
    const int tid = threadIdx.x;
    const int l = tid & 63, w = tid >> 6;
    const int wm = w & 1, wn = w >> 1;
    const int lr = l & 15, lg = l >> 4;
    const int mt = blockIdx.x, nt = blockIdx.y, z = blockIdx.z;

    const u16* Bw = (z == 0) ? wq : (z == 1) ? wk : wv;
    const u16* Ag = xb + (size_t)(mt * 128) * HID;
    const u16* Bg = Bw + (size_t)(nt * 128) * HID;

    f32x4 acc[4][4] = {};
    gemm_mainloop(Ag, Bg, As, Bs, acc);

    const float sc = (z == 0) ? SCALE_Q : 1.0f;
#pragma unroll
    for (int mi = 0; mi < 4; mi++) {
#pragma unroll
        for (int ni = 0; ni < 4; ni++) {
            const int jg = nt * 128 + wn * 64 + ni * 16 + lr;
            const int h = jg >> 6, d = jg & 63;
            const int i0 = mt * 128 + wm * 64 + mi * 16 + lg * 4;
            const int b = i0 >> 9, n0 = i0 & 511;
            if (z == 1) {  // K: [b,h,m,d]
#pragma unroll
                for (int r2 = 0; r2 < 4; r2++)
                    kb[((size_t)(b * NH + h) * SEQ + n0 + r2) * HD + d] = f2bf(acc[mi][ni][r2]);
            } else {       // Q/V: [b,h,d,n] packed along n
                float bb = (z == 2) ? bv[jg] : 0.0f;
                ushort4 pk;
                pk.x = f2bf(fmaf(acc[mi][ni][0], sc, bb));
                pk.y = f2bf(fmaf(acc[mi][ni][1], sc, bb));
                pk.z = f2bf(fmaf(acc[mi][ni][2], sc, bb));
                pk.w = f2bf(fmaf(acc[mi][ni][3], sc, bb));
                u16* O = (z == 0) ? qtb : vtb;
                *(ushort4*)(O + ((size_t)(b * NH + h) * HD + d) * SEQ + n0) = pk;
            }
        }
    }
}

// ---------------- output GEMM: fp32 out + bias (R2 XCD-chunked remap) ----------------
__global__ __launch_bounds__(256, 3) void gemm_out(
    const u16* __restrict__ A, const u16* __restrict__ wo,
    const float* __restrict__ bo, float* __restrict__ Cout)
{
    __shared__ __align__(16) u16 As[3][128 * 32];
    __shared__ __align__(16) u16 Bs[3][128 * 32];
    const int tid = threadIdx.x;
    const int l = tid & 63, w = tid >> 6;
    const int wm = w & 1, wn = w >> 1;
    const int lr = l & 15, lg = l >> 4;

    const int L = blockIdx.x;
    const int xcd = L & 7, s = L >> 3;
    const int nt = s >> 3;
    const int mt = xcd * 8 + (s & 7);

    const u16* Ag = A + (size_t)(mt * 128) * HID;
    const u16* Bg = wo + (size_t)(nt * 128) * HID;

    f32x4 acc[4][4] = {};
    gemm_mainloop(Ag, Bg, As, Bs, acc);

#pragma unroll
    for (int mi = 0; mi < 4; mi++) {
#pragma unroll
        for (int ni = 0; ni < 4; ni++) {
            const int jg = nt * 128 + wn * 64 + ni * 16 + lr;
            float bb = bo[jg];
#pragma unroll
            for (int r2 = 0; r2 < 4; r2++) {
                int ig = mt * 128 + wm * 64 + mi * 16 + lg * 4 + r2;
                Cout[(size_t)ig * HID + jg] = acc[mi][ni][r2] + bb;
            }
        }
    }
}

// ---------------- fused flash attention (R2-exact: bf16 bias, XCD-local decode) ----------------
__device__ __forceinline__ void stage_kv(
    const u16* __restrict__ Kg, const u16* __restrict__ Vg, int mt0,
    u16* Ksb, u16* Vsb, int kr0, int kc0, int kr1, int kc1, int w)
{
    gl2lds16(Kg + (size_t)(mt0 + kr0) * HD + kc0 * 8, Ksb + w * 512);
    gl2lds16(Kg + (size_t)(mt0 + kr1) * HD + kc1 * 8, Ksb + 2048 + w * 512);
    gl2lds16(Vg + (size_t)kr0 * SEQ + mt0 + kc0 * 8, Vsb + w * 512);
    gl2lds16(Vg + (size_t)kr1 * SEQ + mt0 + kc1 * 8, Vsb + 2048 + w * 512);
}

__global__ __launch_bounds__(256, 4) void attn_kernel(
    const u16* __restrict__ qtb, const u16* __restrict__ kb, const u16* __restrict__ vtb,
    const u16* __restrict__ ebb, u16* __restrict__ ob)
{
    __shared__ __align__(16) u16 Ks[2][64 * 64];
    __shared__ __align__(16) u16 Vs[2][64 * 64];
    __shared__ __align__(16) u16 Ps[4][16 * 64];

    const int tid = threadIdx.x;
    const int l = tid & 63, w = tid >> 6;
    const int lr = l & 15, lg = l >> 4;

    // XCD-aware decode (R2): 2 batches per XCD; h outer, qt inner ->
    // K/V(b,h) (256KB, x8 reuse) and bias rows (x12 reuse) stay in own-XCD L2.
    const int L = blockIdx.x;
    const int xcd = L & 7, s = L >> 3;            // s in [0,192)
    const int b = xcd * 2 + (s / 96);
    const int s2 = s % 96;
    const int h = s2 >> 3, qt = s2 & 7;

    const int bh = b * NH + h;
    const int qrow0 = qt * 64 + w * 16;

    const u16* Kg = kb + (size_t)bh * SEQ * HD;
    const u16* Vg = vtb + (size_t)bh * HD * SEQ;
    const u16* Eg = ebb + ((size_t)b * SEQ + qrow0 + lg * 4) * SEQ;

    // staging chunk assignment (swizzled): p = row*8 + (c ^ (row&7))
    const int p0 = tid, p1 = tid + 256;
    const int kr0 = p0 >> 3, kc0 = (p0 & 7) ^ (kr0 & 7);
    const int kr1 = p1 >> 3, kc1 = (p1 & 7) ^ (kr1 & 7);

    stage_kv(Kg, Vg, 0, Ks[0], Vs[0], kr0, kc0, kr1, kc1, w);

    // Q fragments (A-layout) gathered from transposed Q [b,h,d,n]
    const u16* Qg = qtb + (size_t)bh * HD * SEQ + qrow0 + lr;
    bf16x8 qf0, qf1;
#pragma unroll
    for (int j = 0; j < 8; j++) {
        qf0[j] = __builtin_bit_cast(__bf16, Qg[(size_t)(lg * 8 + j) * SEQ]);
        qf1[j] = __builtin_bit_cast(__bf16, Qg[(size_t)(lg * 8 + j + 32) * SEQ]);
    }

    bf16x8 ones;
#pragma unroll
    for (int j = 0; j < 8; j++) ones[j] = __builtin_bit_cast(__bf16, (u16)0x3F80);

    f32x4 oacc[4] = {};
    f32x4 lacc = {};
    float amax[4] = {0.f, 0.f, 0.f, 0.f};

    for (int t = 0; t < 8; t++) {
        const int cur = t & 1;
        const int mt0 = t * 64;
        __syncthreads();  // drains tile-t loads; prev tile's reads done

        // bias loads FIRST (vmcnt-ordered before the prefetch below)
        u16 bl[4][4];
#pragma unroll
        for (int mi = 0; mi < 4; mi++)
#pragma unroll
            for (int r = 0; r < 4; r++)
                bl[mi][r] = Eg[(size_t)r * SEQ + mt0 + mi * 16 + lr];

        if (t < 7)
            stage_kv(Kg, Vg, mt0 + 64, Ks[cur ^ 1], Vs[cur ^ 1], kr0, kc0, kr1, kc1, w);

        // S = (Q*scale) K^T + bias (bias as MFMA C-init); P = exp(S), no max
        float sm[4][4];
#pragma unroll
        for (int mi = 0; mi < 4; mi++) {
            const int row = mi * 16 + lr;
            bf16x8 kf0 = *(const bf16x8*)(Ks[cur] + row * 64 + ((lg ^ (row & 7)) * 8));
            bf16x8 kf1 = *(const bf16x8*)(Ks[cur] + row * 64 + (((4 + lg) ^ (row & 7)) * 8));
            f32x4 s;
#pragma unroll
            for (int r = 0; r < 4; r++) s[r] = bf2f(bl[mi][r]);
            s = __builtin_amdgcn_mfma_f32_16x16x32_bf16(qf0, kf0, s, 0, 0, 0);
            s = __builtin_amdgcn_mfma_f32_16x16x32_bf16(qf1, kf1, s, 0, 0, 0);
#pragma unroll
            for (int r = 0; r < 4; r++) {
                float sv = s[r];
                amax[r] = fmaxf(amax[r], fabsf(sv));
                sm[mi][r] = __expf(sv);
            }
        }

        // P: C-layout -> per-wave swizzled LDS -> A-layout
        u16* Pw = Ps[w];
#pragma unroll
        for (int mi = 0; mi < 4; mi++)
#pragma unroll
            for (int r = 0; r < 4; r++) {
                const int q = lg * 4 + r;
                const int chunk = mi * 2 + (lr >> 3);
                Pw[q * 64 + ((chunk ^ (q & 7)) * 8) + (lr & 7)] = f2bf(sm[mi][r]);
            }

#pragma unroll
        for (int ks = 0; ks < 2; ks++) {
            bf16x8 pf = *(const bf16x8*)(Pw + lr * 64 + (((ks * 4 + lg) ^ (lr & 7)) * 8));
#pragma unroll
            for (int di = 0; di < 4; di++) {
                const int row = di * 16 + lr;
                bf16x8 vf = *(const bf16x8*)(Vs[cur] + row * 64 + (((ks * 4 + lg) ^ (row & 7)) * 8));
                oacc[di] = __builtin_amdgcn_mfma_f32_16x16x32_bf16(pf, vf, oacc[di], 0, 0, 0);
            }
            lacc = __builtin_amdgcn_mfma_f32_16x16x32_bf16(pf, ones, lacc, 0, 0, 0);
        }
    }

#pragma unroll
    for (int r = 0; r < 4; r++) {
        float am = amax[r];
        am = fmaxf(am, __shfl_xor(am, 1));
        am = fmaxf(am, __shfl_xor(am, 2));
        am = fmaxf(am, __shfl_xor(am, 4));
        am = fmaxf(am, __shfl_xor(am, 8));
        float inv = (am > 0.f) ? (1.0f / lacc[r]) : 0.0f;  // all-zero row -> 0 (ref: NaN->0)
        int n = qrow0 + lg * 4 + r;
        u16* orow = ob + ((size_t)b * SEQ + n) * HID + h * HD;
#pragma unroll
        for (int di = 0; di < 4; di++)
            orow[di * 16 + lr] = f2bf(oacc[di][r] * inv);
    }
}

// ---------------- launch ----------------
extern "C" void kernel_launch(void* const* d_in, const int* in_sizes, int n_in,
                              void* d_out, int out_size, void* d_ws, size_t ws_size,
                              hipStream_t stream) {
    (void)in_sizes; (void)n_in; (void)out_size; (void)ws_size;
    const float* x  = (const float*)d_in[0];
    const float* eb = (const float*)d_in[1];
    const float* Wq = (const float*)d_in[2];
    const float* Wk = (const float*)d_in[3];
    const float* Wv = (const float*)d_in[4];
    const float* bv = (const float*)d_in[5];
    const float* Wo = (const float*)d_in[6];
    const float* bo = (const float*)d_in[7];
    float* out = (float*)d_out;

    const int NX = BATCH * SEQ * HID;   // 6291456
    const int NW = HID * HID;           // 589824
    const int NE = BATCH * SEQ * SEQ;   // 4194304
    u16* ws   = (u16*)d_ws;
    u16* xb   = ws;                 // contiguous cvt region: [x | eb | wq | wk | wv | wo]
    u16* ebb  = xb + NX;
    u16* wqb  = ebb + NE;
    u16* wkb  = wqb + NW;
    u16* wvb  = wkb + NW;
    u16* wob  = wvb + NW;
    u16* qtb  = wob + NW;
    u16* kb   = qtb + NX;
    u16* vtb  = kb + NX;
    u16* obuf = vtb + NX;

    cvt_all<<<NXB + NEB + 4 * NWB, 256, 0, stream>>>(x, eb, Wq, Wk, Wv, Wo, ws);

    gemm_qkv<<<dim3(64, 6, 3), 256, 0, stream>>>(xb, wqb, wkb, wvb, bv, qtb, kb, vtb);

    attn_kernel<<<1536, 256, 0, stream>>>(qtb, kb, vtb, ebb, obuf);

    gemm_out<<<384, 256, 0, stream>>>(obuf, wob, bo, out);
}

// Round 9
// 198.360 us; speedup vs baseline: 1.0848x; 1.0096x over previous
//
#include <hip/hip_runtime.h>
#include <stdint.h>

typedef unsigned short u16;
typedef unsigned int u32;
typedef __bf16 bf16x8 __attribute__((ext_vector_type(8)));
typedef float f32x4 __attribute__((ext_vector_type(4)));

#define NH 12
#define HD 64
#define SEQ 512
#define BATCH 16
#define HID 768
#define SCALE_Q 0.03608439182435161f  // 768^-0.5

__device__ __forceinline__ u16 f2bf(float f) {
    u32 u = __builtin_bit_cast(u32, f);
    u32 r = (u + 0x7FFFu + ((u >> 16) & 1u)) >> 16;
    return (u16)r;
}
__device__ __forceinline__ float bf2f(u16 h) {
    return __builtin_bit_cast(float, (u32)h << 16);
}

// async global -> LDS, 16B per lane; lds dest = wave-uniform base + lane*16
__device__ __forceinline__ void gl2lds16(const u16* g, u16* lds_base) {
    __builtin_amdgcn_global_load_lds(
        (const __attribute__((address_space(1))) u32*)g,
        (__attribute__((address_space(3))) u32*)lds_base, 16, 0, 0);
}

// ---------------- fused fp32 -> bf16 convert (all 6 tensors, one launch) ----------------
#define NXB 6144   // NX/1024
#define NEB 4096   // NE/1024
#define NWB 576    // NW/1024
__global__ void cvt_all(const float* __restrict__ x, const float* __restrict__ eb,
                        const float* __restrict__ w0, const float* __restrict__ w1,
                        const float* __restrict__ w2, const float* __restrict__ w3,
                        u16* __restrict__ dst) {
    int b = blockIdx.x;
    const float* s; int sb;
    if (b < NXB) { s = x; sb = 0; }
    else if (b < NXB + NEB) { s = eb; sb = NXB; }
    else if (b < NXB + NEB + NWB) { s = w0; sb = NXB + NEB; }
    else if (b < NXB + NEB + 2 * NWB) { s = w1; sb = NXB + NEB + NWB; }
    else if (b < NXB + NEB + 3 * NWB) { s = w2; sb = NXB + NEB + 2 * NWB; }
    else { s = w3; sb = NXB + NEB + 3 * NWB; }
    int li = (b - sb) * 1024 + threadIdx.x * 4;
    float4 v = *(const float4*)(s + li);
    ushort4 o;
    o.x = f2bf(v.x); o.y = f2bf(v.y); o.z = f2bf(v.z); o.w = f2bf(v.w);
    *(ushort4*)(dst + (size_t)b * 1024 + threadIdx.x * 4) = o;
}

// ---------------- NT GEMM mainloop: 3-buffer ring, prefetch distance 2, counted vmcnt ----------------
// (R1 verbatim — measured 54-58 us for gemm_qkv; at the m97-structure ceiling for this shape)
__device__ __forceinline__ void stage_gemm(
    const u16* __restrict__ Ag, const u16* __restrict__ Bg, int k0,
    u16* As, u16* Bs, int r0, int q0, int r1, int q1, int w)
{
    gl2lds16(Ag + (size_t)r0 * HID + k0 + q0, As + w * 512);
    gl2lds16(Ag + (size_t)r1 * HID + k0 + q1, As + 2048 + w * 512);
    gl2lds16(Bg + (size_t)r0 * HID + k0 + q0, Bs + w * 512);
    gl2lds16(Bg + (size_t)r1 * HID + k0 + q1, Bs + 2048 + w * 512);
}

__device__ __forceinline__ void gemm_mainloop(
    const u16* __restrict__ Ag, const u16* __restrict__ Bg,
    u16 (*As)[128 * 32], u16 (*Bs)[128 * 32], f32x4 (&acc)[4][4])
{
    const int tid = threadIdx.x;
    const int l = tid & 63, w = tid >> 6;
    const int wm = w & 1, wn = w >> 1;
    const int lr = l & 15, lg = l >> 4;

    const int c0 = tid, c1 = tid + 256;
    const int r0 = c0 >> 2, q0 = (((c0 & 3) ^ ((r0 >> 1) & 3)) * 8);
    const int r1 = c1 >> 2, q1 = (((c1 & 3) ^ ((r1 >> 1) & 3)) * 8);

    const int sA = (lg ^ ((lr >> 1) & 3)) * 8;

    stage_gemm(Ag, Bg, 0, As[0], Bs[0], r0, q0, r1, q1, w);
    stage_gemm(Ag, Bg, 32, As[1], Bs[1], r0, q0, r1, q1, w);

    int cur = 0;
    for (int i = 0; i < 24; i++) {
        if (i < 23)
            asm volatile("s_waitcnt vmcnt(4) lgkmcnt(0)" ::: "memory");
        else
            asm volatile("s_waitcnt vmcnt(0) lgkmcnt(0)" ::: "memory");
        __builtin_amdgcn_s_barrier();
        __builtin_amdgcn_sched_barrier(0);

        int nxt = cur + 2; if (nxt >= 3) nxt -= 3;
        if (i < 22)
            stage_gemm(Ag, Bg, (i + 2) * 32, As[nxt], Bs[nxt], r0, q0, r1, q1, w);

        bf16x8 af[4], bfr[4];
#pragma unroll
        for (int mi = 0; mi < 4; mi++)
            af[mi] = *(const bf16x8*)(As[cur] + (wm * 64 + mi * 16 + lr) * 32 + sA);
#pragma unroll
        for (int ni = 0; ni < 4; ni++)
            bfr[ni] = *(const bf16x8*)(Bs[cur] + (wn * 64 + ni * 16 + lr) * 32 + sA);
#pragma unroll
        for (int mi = 0; mi < 4; mi++)
#pragma unroll
            for (int ni = 0; ni < 4; ni++)
                acc[mi][ni] = __builtin_amdgcn_mfma_f32_16x16x32_bf16(af[mi], bfr[ni], acc[mi][ni], 0, 0, 0);

        cur += 1; if (cur >= 3) cur -= 3;
    }
}

// ---------------- fused QKV GEMM (R1 linear decode: mt fastest => A panels XCD-local) ----------------
__global__ __launch_bounds__(256, 3) void gemm_qkv(
    const u16* __restrict__ xb, const u16* __restrict__ wq,
    const u16* __restrict__ wk, const u16* __restrict__ wv,
    const float* __restrict__ bv,
    u16* __restrict__ qtb, u16* __restrict__ kb, u16* __restrict__ vtb)
{
    __shared__ __align__(16) u16 As[3][128 * 32];
    __shared__ __align__(16) u16 Bs[3][128 * 32];
    const int tid = threadIdx.x;
    const int l = tid & 63, w = tid >> 6;
    const int wm = w & 1, wn = w >> 1;
    const int lr = l & 15, lg = l >> 4;
    const int mt = blockIdx.x, nt = blockIdx.y, z = blockIdx.z;

    const u16* Bw = (z == 0) ? wq : (z == 1) ? wk : wv;
    const u16* Ag = xb + (size_t)(mt * 128) * HID;
    const u16* Bg = Bw + (size_t)(nt * 128) * HID;

    f32x4 acc[4][4] = {};
    gemm_mainloop(Ag, Bg, As, Bs, acc);

    const float sc = (z == 0) ? SCALE_Q : 1.0f;
#pragma unroll
    for (int mi = 0; mi < 4; mi++) {
#pragma unroll
        for (int ni = 0; ni < 4; ni++) {
            const int jg = nt * 128 + wn * 64 + ni * 16 + lr;
            const int h = jg >> 6, d = jg & 63;
            const int i0 = mt * 128 + wm * 64 + mi * 16 + lg * 4;
            const int b = i0 >> 9, n0 = i0 & 511;
            if (z == 1) {  // K: [b,h,m,d]
#pragma unroll
                for (int r2 = 0; r2 < 4; r2++)
                    kb[((size_t)(b * NH + h) * SEQ + n0 + r2) * HD + d] = f2bf(acc[mi][ni][r2]);
            } else {       // Q/V: [b,h,d,n] packed along n
                float bb = (z == 2) ? bv[jg] : 0.0f;
                ushort4 pk;
                pk.x = f2bf(fmaf(acc[mi][ni][0], sc, bb));
                pk.y = f2bf(fmaf(acc[mi][ni][1], sc, bb));
                pk.z = f2bf(fmaf(acc[mi][ni][2], sc, bb));
                pk.w = f2bf(fmaf(acc[mi][ni][3], sc, bb));
                u16* O = (z == 0) ? qtb : vtb;
                *(ushort4*)(O + ((size_t)(b * NH + h) * HD + d) * SEQ + n0) = pk;
            }
        }
    }
}

// ---------------- output GEMM: fp32 out + bias (R2 XCD-chunked remap) ----------------
__global__ __launch_bounds__(256, 3) void gemm_out(
    const u16* __restrict__ A, const u16* __restrict__ wo,
    const float* __restrict__ bo, float* __restrict__ Cout)
{
    __shared__ __align__(16) u16 As[3][128 * 32];
    __shared__ __align__(16) u16 Bs[3][128 * 32];
    const int tid = threadIdx.x;
    const int l = tid & 63, w = tid >> 6;
    const int wm = w & 1, wn = w >> 1;
    const int lr = l & 15, lg = l >> 4;

    const int L = blockIdx.x;
    const int xcd = L & 7, s = L >> 3;
    const int nt = s >> 3;
    const int mt = xcd * 8 + (s & 7);

    const u16* Ag = A + (size_t)(mt * 128) * HID;
    const u16* Bg = wo + (size_t)(nt * 128) * HID;

    f32x4 acc[4][4] = {};
    gemm_mainloop(Ag, Bg, As, Bs, acc);

#pragma unroll
    for (int mi = 0; mi < 4; mi++) {
#pragma unroll
        for (int ni = 0; ni < 4; ni++) {
            const int jg = nt * 128 + wn * 64 + ni * 16 + lr;
            float bb = bo[jg];
#pragma unroll
            for (int r2 = 0; r2 < 4; r2++) {
                int ig = mt * 128 + wm * 64 + mi * 16 + lg * 4 + r2;
                Cout[(size_t)ig * HID + jg] = acc[mi][ni][r2] + bb;
            }
        }
    }
}

// ---------------- fused flash attention: R2 datapath, 2 Q-blocks per wave (R5 best, 197.6us) ----------------
// Block covers 128 q-rows (wave w: rows qt*128 + w*16 and +64). K/V LDS tiles + vf/kf
// fragment reads serve BOTH q-blocks -> K/V global traffic and barrier count halve.
__device__ __forceinline__ void stage_kv(
    const u16* __restrict__ Kg, const u16* __restrict__ Vg, int mt0,
    u16* Ksb, u16* Vsb, int kr0, int kc0, int kr1, int kc1, int w)
{
    gl2lds16(Kg + (size_t)(mt0 + kr0) * HD + kc0 * 8, Ksb + w * 512);
    gl2lds16(Kg + (size_t)(mt0 + kr1) * HD + kc1 * 8, Ksb + 2048 + w * 512);
    gl2lds16(Vg + (size_t)kr0 * SEQ + mt0 + kc0 * 8, Vsb + w * 512);
    gl2lds16(Vg + (size_t)kr1 * SEQ + mt0 + kc1 * 8, Vsb + 2048 + w * 512);
}

__global__ __launch_bounds__(256, 3) void attn_kernel(
    const u16* __restrict__ qtb, const u16* __restrict__ kb, const u16* __restrict__ vtb,
    const u16* __restrict__ ebb, u16* __restrict__ ob)
{
    __shared__ __align__(16) u16 Ks[2][64 * 64];
    __shared__ __align__(16) u16 Vs[2][64 * 64];
    __shared__ __align__(16) u16 Ps[8][16 * 64];   // 2 slabs per wave (qb0: w, qb1: 4+w)

    const int tid = threadIdx.x;
    const int l = tid & 63, w = tid >> 6;
    const int lr = l & 15, lg = l >> 4;

    // XCD-aware decode: 768 blocks = 8 xcd * (2 b * 12 h * 4 qt); h outer, qt inner.
    const int L = blockIdx.x;
    const int xcd = L & 7, s = L >> 3;            // s in [0,96)
    const int b = xcd * 2 + (s / 48);
    const int s2 = s % 48;
    const int h = s2 >> 2, qt = s2 & 3;

    const int bh = b * NH + h;
    const int qrow0 = qt * 128 + w * 16;          // qb0 rows; qb1 = qrow0 + 64

    const u16* Kg = kb + (size_t)bh * SEQ * HD;
    const u16* Vg = vtb + (size_t)bh * HD * SEQ;
    const u16* Eg0 = ebb + ((size_t)b * SEQ + qrow0 + lg * 4) * SEQ;
    const u16* Eg1 = Eg0 + (size_t)64 * SEQ;

    // staging chunk assignment (swizzled): p = row*8 + (c ^ (row&7))
    const int p0 = tid, p1 = tid + 256;
    const int kr0 = p0 >> 3, kc0 = (p0 & 7) ^ (kr0 & 7);
    const int kr1 = p1 >> 3, kc1 = (p1 & 7) ^ (kr1 & 7);

    stage_kv(Kg, Vg, 0, Ks[0], Vs[0], kr0, kc0, kr1, kc1, w);

    // Q fragments (A-layout) gathered from transposed Q [b,h,d,n]; two q-blocks
    const u16* Qg = qtb + (size_t)bh * HD * SEQ + qrow0 + lr;
    bf16x8 qA0, qA1, qB0, qB1;
#pragma unroll
    for (int j = 0; j < 8; j++) {
        qA0[j] = __builtin_bit_cast(__bf16, Qg[(size_t)(lg * 8 + j) * SEQ]);
        qA1[j] = __builtin_bit_cast(__bf16, Qg[(size_t)(lg * 8 + j + 32) * SEQ]);
        qB0[j] = __builtin_bit_cast(__bf16, Qg[(size_t)(lg * 8 + j) * SEQ + 64]);
        qB1[j] = __builtin_bit_cast(__bf16, Qg[(size_t)(lg * 8 + j + 32) * SEQ + 64]);
    }

    bf16x8 ones;
#pragma unroll
    for (int j = 0; j < 8; j++) ones[j] = __builtin_bit_cast(__bf16, (u16)0x3F80);

    f32x4 oacc0[4] = {}, oacc1[4] = {};
    f32x4 lacc0 = {}, lacc1 = {};
    float amax0[4] = {0.f, 0.f, 0.f, 0.f};
    float amax1[4] = {0.f, 0.f, 0.f, 0.f};
    u16* Pw0 = Ps[w];
    u16* Pw1 = Ps[4 + w];

    for (int t = 0; t < 8; t++) {
        const int cur = t & 1;
        const int mt0 = t * 64;
        __syncthreads();  // drains tile-t loads; prev tile's reads done

        // bias loads FIRST (vmcnt-ordered before the prefetch below)
        u16 bl0[4][4], bl1[4][4];
#pragma unroll
        for (int mi = 0; mi < 4; mi++)
#pragma unroll
            for (int r = 0; r < 4; r++) {
                bl0[mi][r] = Eg0[(size_t)r * SEQ + mt0 + mi * 16 + lr];
                bl1[mi][r] = Eg1[(size_t)r * SEQ + mt0 + mi * 16 + lr];
            }

        if (t < 7)
            stage_kv(Kg, Vg, mt0 + 64, Ks[cur ^ 1], Vs[cur ^ 1], kr0, kc0, kr1, kc1, w);

        // S = (Q*scale) K^T + bias (bias as MFMA C-init); P = exp(S), no max.
        // kf fragments read ONCE, feed both q-blocks.
        float sm0[4][4], sm1[4][4];
#pragma unroll
        for (int mi = 0; mi < 4; mi++) {
            const int row = mi * 16 + lr;
            bf16x8 kf0 = *(const bf16x8*)(Ks[cur] + row * 64 + ((lg ^ (row & 7)) * 8));
            bf16x8 kf1 = *(const bf16x8*)(Ks[cur] + row * 64 + (((4 + lg) ^ (row & 7)) * 8));
            f32x4 s0, s1;
#pragma unroll
            for (int r = 0; r < 4; r++) { s0[r] = bf2f(bl0[mi][r]); s1[r] = bf2f(bl1[mi][r]); }
            s0 = __builtin_amdgcn_mfma_f32_16x16x32_bf16(qA0, kf0, s0, 0, 0, 0);
            s0 = __builtin_amdgcn_mfma_f32_16x16x32_bf16(qA1, kf1, s0, 0, 0, 0);
            s1 = __builtin_amdgcn_mfma_f32_16x16x32_bf16(qB0, kf0, s1, 0, 0, 0);
            s1 = __builtin_amdgcn_mfma_f32_16x16x32_bf16(qB1, kf1, s1, 0, 0, 0);
#pragma unroll
            for (int r = 0; r < 4; r++) {
                float a = s0[r], c = s1[r];
                amax0[r] = fmaxf(amax0[r], fabsf(a));
                amax1[r] = fmaxf(amax1[r], fabsf(c));
                sm0[mi][r] = __expf(a);
                sm1[mi][r] = __expf(c);
            }
        }

        // P: C-layout -> per-wave swizzled LDS (two slabs) -> A-layout
#pragma unroll
        for (int mi = 0; mi < 4; mi++)
#pragma unroll
            for (int r = 0; r < 4; r++) {
                const int q = lg * 4 + r;
                const int chunk = mi * 2 + (lr >> 3);
                const int off = q * 64 + ((chunk ^ (q & 7)) * 8) + (lr & 7);
                Pw0[off] = f2bf(sm0[mi][r]);
                Pw1[off] = f2bf(sm1[mi][r]);
            }

        // PV: vf fragments read ONCE, feed both q-blocks.
#pragma unroll
        for (int ks = 0; ks < 2; ks++) {
            bf16x8 pf0 = *(const bf16x8*)(Pw0 + lr * 64 + (((ks * 4 + lg) ^ (lr & 7)) * 8));
            bf16x8 pf1 = *(const bf16x8*)(Pw1 + lr * 64 + (((ks * 4 + lg) ^ (lr & 7)) * 8));
#pragma unroll
            for (int di = 0; di < 4; di++) {
                const int row = di * 16 + lr;
                bf16x8 vf = *(const bf16x8*)(Vs[cur] + row * 64 + (((ks * 4 + lg) ^ (row & 7)) * 8));
                oacc0[di] = __builtin_amdgcn_mfma_f32_16x16x32_bf16(pf0, vf, oacc0[di], 0, 0, 0);
                oacc1[di] = __builtin_amdgcn_mfma_f32_16x16x32_bf16(pf1, vf, oacc1[di], 0, 0, 0);
            }
            lacc0 = __builtin_amdgcn_mfma_f32_16x16x32_bf16(pf0, ones, lacc0, 0, 0, 0);
            lacc1 = __builtin_amdgcn_mfma_f32_16x16x32_bf16(pf1, ones, lacc1, 0, 0, 0);
        }
    }

#pragma unroll
    for (int r = 0; r < 4; r++) {
        float am0 = amax0[r], am1 = amax1[r];
        am0 = fmaxf(am0, __shfl_xor(am0, 1));
        am0 = fmaxf(am0, __shfl_xor(am0, 2));
        am0 = fmaxf(am0, __shfl_xor(am0, 4));
        am0 = fmaxf(am0, __shfl_xor(am0, 8));
        am1 = fmaxf(am1, __shfl_xor(am1, 1));
        am1 = fmaxf(am1, __shfl_xor(am1, 2));
        am1 = fmaxf(am1, __shfl_xor(am1, 4));
        am1 = fmaxf(am1, __shfl_xor(am1, 8));
        float inv0 = (am0 > 0.f) ? (1.0f / lacc0[r]) : 0.0f;  // all-zero row -> 0 (ref: NaN->0)
        float inv1 = (am1 > 0.f) ? (1.0f / lacc1[r]) : 0.0f;
        int n0 = qrow0 + lg * 4 + r;
        u16* orow0 = ob + ((size_t)b * SEQ + n0) * HID + h * HD;
        u16* orow1 = ob + ((size_t)b * SEQ + n0 + 64) * HID + h * HD;
#pragma unroll
        for (int di = 0; di < 4; di++) {
            orow0[di * 16 + lr] = f2bf(oacc0[di][r] * inv0);
            orow1[di * 16 + lr] = f2bf(oacc1[di][r] * inv1);
        }
    }
}

// ---------------- launch ----------------
extern "C" void kernel_launch(void* const* d_in, const int* in_sizes, int n_in,
                              void* d_out, int out_size, void* d_ws, size_t ws_size,
                              hipStream_t stream) {
    (void)in_sizes; (void)n_in; (void)out_size; (void)ws_size;
    const float* x  = (const float*)d_in[0];
    const float* eb = (const float*)d_in[1];
    const float* Wq = (const float*)d_in[2];
    const float* Wk = (const float*)d_in[3];
    const float* Wv = (const float*)d_in[4];
    const float* bv = (const float*)d_in[5];
    const float* Wo = (const float*)d_in[6];
    const float* bo = (const float*)d_in[7];
    float* out = (float*)d_out;

    const int NX = BATCH * SEQ * HID;   // 6291456
    const int NW = HID * HID;           // 589824
    const int NE = BATCH * SEQ * SEQ;   // 4194304
    u16* ws   = (u16*)d_ws;
    u16* xb   = ws;                 // contiguous cvt region: [x | eb | wq | wk | wv | wo]
    u16* ebb  = xb + NX;
    u16* wqb  = ebb + NE;
    u16* wkb  = wqb + NW;
    u16* wvb  = wkb + NW;
    u16* wob  = wvb + NW;
    u16* qtb  = wob + NW;
    u16* kb   = qtb + NX;
    u16* vtb  = kb + NX;
    u16* obuf = vtb + NX;

    cvt_all<<<NXB + NEB + 4 * NWB, 256, 0, stream>>>(x, eb, Wq, Wk, Wv, Wo, ws);

    gemm_qkv<<<dim3(64, 6, 3), 256, 0, stream>>>(xb, wqb, wkb, wvb, bv, qtb, kb, vtb);

    attn_kernel<<<768, 256, 0, stream>>>(qtb, kb, vtb, ebb, obuf);

    gemm_out<<<384, 256, 0, stream>>>(obuf, wob, bo, out);
}

// Round 10
// 197.615 us; speedup vs baseline: 1.0888x; 1.0038x over previous
//
#include <hip/hip_runtime.h>
#include <stdint.h>

typedef unsigned short u16;
typedef unsigned int u32;
typedef __bf16 bf16x8 __attribute__((ext_vector_type(8)));
typedef float f32x4 __attribute__((ext_vector_type(4)));

#define NH 12
#define HD 64
#define SEQ 512
#define BATCH 16
#define HID 768
#define SCALE_Q 0.03608439182435161f  // 768^-0.5

__device__ __forceinline__ u16 f2bf(float f) {
    u32 u = __builtin_bit_cast(u32, f);
    u32 r = (u + 0x7FFFu + ((u >> 16) & 1u)) >> 16;
    return (u16)r;
}
__device__ __forceinline__ float bf2f(u16 h) {
    return __builtin_bit_cast(float, (u32)h << 16);
}

// async global -> LDS, 16B per lane; lds dest = wave-uniform base + lane*16
__device__ __forceinline__ void gl2lds16(const u16* g, u16* lds_base) {
    __builtin_amdgcn_global_load_lds(
        (const __attribute__((address_space(1))) u32*)g,
        (__attribute__((address_space(3))) u32*)lds_base, 16, 0, 0);
}

// ---------------- fused fp32 -> bf16 convert (all 6 tensors, one launch) ----------------
#define NXB 6144   // NX/1024
#define NEB 4096   // NE/1024
#define NWB 576    // NW/1024
__global__ void cvt_all(const float* __restrict__ x, const float* __restrict__ eb,
                        const float* __restrict__ w0, const float* __restrict__ w1,
                        const float* __restrict__ w2, const float* __restrict__ w3,
                        u16* __restrict__ dst) {
    int b = blockIdx.x;
    const float* s; int sb;
    if (b < NXB) { s = x; sb = 0; }
    else if (b < NXB + NEB) { s = eb; sb = NXB; }
    else if (b < NXB + NEB + NWB) { s = w0; sb = NXB + NEB; }
    else if (b < NXB + NEB + 2 * NWB) { s = w1; sb = NXB + NEB + NWB; }
    else if (b < NXB + NEB + 3 * NWB) { s = w2; sb = NXB + NEB + 2 * NWB; }
    else { s = w3; sb = NXB + NEB + 3 * NWB; }
    int li = (b - sb) * 1024 + threadIdx.x * 4;
    float4 v = *(const float4*)(s + li);
    ushort4 o;
    o.x = f2bf(v.x); o.y = f2bf(v.y); o.z = f2bf(v.z); o.w = f2bf(v.w);
    *(ushort4*)(dst + (size_t)b * 1024 + threadIdx.x * 4) = o;
}

// ================= z-MERGED QKV GEMM: 768 threads (12 waves), one A-stage feeds 3 z =================
// Waves 0-3: z=0 (Q), 4-7: z=1 (K), 8-11: z=2 (V). Per K-step stage A (512 chunks) + 3 B tiles
// (1536 chunks) = 2048 chunks over 768 threads in <=3 wave-uniform passes. 3-buffer ring,
// prefetch distance 2, per-wave counted vmcnt (own loads per step: 3 for w<8, 2 for w>=8).
// Chunk slot map (disjoint+complete): A <- p0 w0-7; B0 <- p0 w8-11 (slots 0-255) + p1 w0-3
// (slots 256-511); B1 <- p1 w4-11; B2 <- p2 w0-7. Slot sl: row=sl>>2, fetched chunk
// q=((sl&3)^((row>>1)&3))*8 (same XOR swizzle as the proven 4-wave mainloop).
__global__ __launch_bounds__(768, 3) void gemm_qkv(
    const u16* __restrict__ xb, const u16* __restrict__ wq,
    const u16* __restrict__ wk, const u16* __restrict__ wv,
    const float* __restrict__ bv,
    u16* __restrict__ qtb, u16* __restrict__ kb, u16* __restrict__ vtb)
{
    __shared__ __align__(16) u16 As[3][4096];        // 24 KB
    __shared__ __align__(16) u16 Bs[3][3][4096];     // [z][buf], 72 KB
    const int tid = threadIdx.x;
    const int l = tid & 63, w = tid >> 6;            // w in 0..11
    const int wz = w >> 2, wl = w & 3;
    const int wm = wl & 1, wn = wl >> 1;
    const int lr = l & 15, lg = l >> 4;
    const int mt = blockIdx.x, nt = blockIdx.y;

    const u16* Ag = xb + (size_t)(mt * 128) * HID;
    const u16* Bg0 = wq + (size_t)(nt * 128) * HID;
    const u16* Bg1 = wk + (size_t)(nt * 128) * HID;
    const u16* Bg2 = wv + (size_t)(nt * 128) * HID;

    // ---- staging source (row,q) per pass + wave-uniform array/base selection ----
    // pass 0
    const int sl0 = (w < 8) ? (w * 64 + l) : ((w - 8) * 64 + l);
    const int r0 = sl0 >> 2, q0 = (((sl0 & 3) ^ ((r0 >> 1) & 3)) * 8);
    const u16* s0 = ((w < 8) ? Ag : Bg0) + (size_t)r0 * HID + q0;
    const int d0off = (w < 8) ? (w * 512) : ((w - 8) * 512);   // into As or Bs[0]
    // pass 1
    const int sl1 = (w < 4) ? (256 + w * 64 + l) : ((w - 4) * 64 + l);
    const int r1 = sl1 >> 2, q1 = (((sl1 & 3) ^ ((r1 >> 1) & 3)) * 8);
    const u16* s1 = ((w < 4) ? Bg0 : Bg1) + (size_t)r1 * HID + q1;
    const int d1off = (w < 4) ? (2048 + w * 512) : ((w - 4) * 512);  // into Bs[0] or Bs[1]
    // pass 2 (waves 0-7 only)
    const int sl2 = w * 64 + l;
    const int r2s = sl2 >> 2, q2 = (((sl2 & 3) ^ ((r2s >> 1) & 3)) * 8);
    const u16* s2 = Bg2 + (size_t)r2s * HID + q2;
    const int d2off = w * 512;                                   // into Bs[2]

    const int sA = (lg ^ ((lr >> 1) & 3)) * 8;

#define STAGE_QKV(k0, buf)                                                      \
    do {                                                                        \
        gl2lds16(s0 + (k0), ((w < 8) ? As[buf] : Bs[0][buf]) + d0off);          \
        gl2lds16(s1 + (k0), ((w < 4) ? Bs[0][buf] : Bs[1][buf]) + d1off);       \
        if (w < 8) gl2lds16(s2 + (k0), Bs[2][buf] + d2off);                     \
    } while (0)

    STAGE_QKV(0, 0);
    STAGE_QKV(32, 1);

    f32x4 acc[4][4] = {};
    int cur = 0;
    for (int i = 0; i < 24; i++) {
        // wait own stage(i) complete; stage(i+1)'s loads (3 or 2) stay in flight
        if (i < 23) {
            if (w < 8) asm volatile("s_waitcnt vmcnt(3) lgkmcnt(0)" ::: "memory");
            else       asm volatile("s_waitcnt vmcnt(2) lgkmcnt(0)" ::: "memory");
        } else {
            asm volatile("s_waitcnt vmcnt(0) lgkmcnt(0)" ::: "memory");
        }
        __builtin_amdgcn_s_barrier();
        __builtin_amdgcn_sched_barrier(0);

        int nxt = cur + 2; if (nxt >= 3) nxt -= 3;
        if (i < 22)
            STAGE_QKV((i + 2) * 32, nxt);

        bf16x8 af[4], bfr[4];
#pragma unroll
        for (int mi = 0; mi < 4; mi++)
            af[mi] = *(const bf16x8*)(As[cur] + (wm * 64 + mi * 16 + lr) * 32 + sA);
#pragma unroll
        for (int ni = 0; ni < 4; ni++)
            bfr[ni] = *(const bf16x8*)(Bs[wz][cur] + (wn * 64 + ni * 16 + lr) * 32 + sA);
#pragma unroll
        for (int mi = 0; mi < 4; mi++)
#pragma unroll
            for (int ni = 0; ni < 4; ni++)
                acc[mi][ni] = __builtin_amdgcn_mfma_f32_16x16x32_bf16(af[mi], bfr[ni], acc[mi][ni], 0, 0, 0);

        cur += 1; if (cur >= 3) cur -= 3;
    }
#undef STAGE_QKV

    const float sc = (wz == 0) ? SCALE_Q : 1.0f;
#pragma unroll
    for (int mi = 0; mi < 4; mi++) {
#pragma unroll
        for (int ni = 0; ni < 4; ni++) {
            const int jg = nt * 128 + wn * 64 + ni * 16 + lr;
            const int h = jg >> 6, d = jg & 63;
            const int i0 = mt * 128 + wm * 64 + mi * 16 + lg * 4;
            const int b = i0 >> 9, n0 = i0 & 511;
            if (wz == 1) {  // K: [b,h,m,d]
#pragma unroll
                for (int r2 = 0; r2 < 4; r2++)
                    kb[((size_t)(b * NH + h) * SEQ + n0 + r2) * HD + d] = f2bf(acc[mi][ni][r2]);
            } else {        // Q/V: [b,h,d,n] packed along n
                float bb = (wz == 2) ? bv[jg] : 0.0f;
                ushort4 pk;
                pk.x = f2bf(fmaf(acc[mi][ni][0], sc, bb));
                pk.y = f2bf(fmaf(acc[mi][ni][1], sc, bb));
                pk.z = f2bf(fmaf(acc[mi][ni][2], sc, bb));
                pk.w = f2bf(fmaf(acc[mi][ni][3], sc, bb));
                u16* O = (wz == 0) ? qtb : vtb;
                *(ushort4*)(O + ((size_t)(b * NH + h) * HD + d) * SEQ + n0) = pk;
            }
        }
    }
}

// ---------------- 128x128 NT GEMM mainloop (gemm_out): 3-buffer ring, distance 2 ----------------
__device__ __forceinline__ void stage_gemm(
    const u16* __restrict__ Ag, const u16* __restrict__ Bg, int k0,
    u16* As, u16* Bs, int r0, int q0, int r1, int q1, int w)
{
    gl2lds16(Ag + (size_t)r0 * HID + k0 + q0, As + w * 512);
    gl2lds16(Ag + (size_t)r1 * HID + k0 + q1, As + 2048 + w * 512);
    gl2lds16(Bg + (size_t)r0 * HID + k0 + q0, Bs + w * 512);
    gl2lds16(Bg + (size_t)r1 * HID + k0 + q1, Bs + 2048 + w * 512);
}

__device__ __forceinline__ void gemm_mainloop(
    const u16* __restrict__ Ag, const u16* __restrict__ Bg,
    u16 (*As)[128 * 32], u16 (*Bs)[128 * 32], f32x4 (&acc)[4][4])
{
    const int tid = threadIdx.x;
    const int l = tid & 63, w = tid >> 6;
    const int wm = w & 1, wn = w >> 1;
    const int lr = l & 15, lg = l >> 4;

    const int c0 = tid, c1 = tid + 256;
    const int r0 = c0 >> 2, q0 = (((c0 & 3) ^ ((r0 >> 1) & 3)) * 8);
    const int r1 = c1 >> 2, q1 = (((c1 & 3) ^ ((r1 >> 1) & 3)) * 8);

    const int sA = (lg ^ ((lr >> 1) & 3)) * 8;

    stage_gemm(Ag, Bg, 0, As[0], Bs[0], r0, q0, r1, q1, w);
    stage_gemm(Ag, Bg, 32, As[1], Bs[1], r0, q0, r1, q1, w);

    int cur = 0;
    for (int i = 0; i < 24; i++) {
        if (i < 23)
            asm volatile("s_waitcnt vmcnt(4) lgkmcnt(0)" ::: "memory");
        else
            asm volatile("s_waitcnt vmcnt(0) lgkmcnt(0)" ::: "memory");
        __builtin_amdgcn_s_barrier();
        __builtin_amdgcn_sched_barrier(0);

        int nxt = cur + 2; if (nxt >= 3) nxt -= 3;
        if (i < 22)
            stage_gemm(Ag, Bg, (i + 2) * 32, As[nxt], Bs[nxt], r0, q0, r1, q1, w);

        bf16x8 af[4], bfr[4];
#pragma unroll
        for (int mi = 0; mi < 4; mi++)
            af[mi] = *(const bf16x8*)(As[cur] + (wm * 64 + mi * 16 + lr) * 32 + sA);
#pragma unroll
        for (int ni = 0; ni < 4; ni++)
            bfr[ni] = *(const bf16x8*)(Bs[cur] + (wn * 64 + ni * 16 + lr) * 32 + sA);
#pragma unroll
        for (int mi = 0; mi < 4; mi++)
#pragma unroll
            for (int ni = 0; ni < 4; ni++)
                acc[mi][ni] = __builtin_amdgcn_mfma_f32_16x16x32_bf16(af[mi], bfr[ni], acc[mi][ni], 0, 0, 0);

        cur += 1; if (cur >= 3) cur -= 3;
    }
}

// ---------------- output GEMM: fp32 out + bias (R2 XCD-chunked remap) ----------------
__global__ __launch_bounds__(256, 3) void gemm_out(
    const u16* __restrict__ A, const u16* __restrict__ wo,
    const float* __restrict__ bo, float* __restrict__ Cout)
{
    __shared__ __align__(16) u16 As[3][128 * 32];
    __shared__ __align__(16) u16 Bs[3][128 * 32];
    const int tid = threadIdx.x;
    const int l = tid & 63, w = tid >> 6;
    const int wm = w & 1, wn = w >> 1;
    const int lr = l & 15, lg = l >> 4;

    const int L = blockIdx.x;
    const int xcd = L & 7, s = L >> 3;
    const int nt = s >> 3;
    const int mt = xcd * 8 + (s & 7);

    const u16* Ag = A + (size_t)(mt * 128) * HID;
    const u16* Bg = wo + (size_t)(nt * 128) * HID;

    f32x4 acc[4][4] = {};
    gemm_mainloop(Ag, Bg, As, Bs, acc);

#pragma unroll
    for (int mi = 0; mi < 4; mi++) {
#pragma unroll
        for (int ni = 0; ni < 4; ni++) {
            const int jg = nt * 128 + wn * 64 + ni * 16 + lr;
            float bb = bo[jg];
#pragma unroll
            for (int r2 = 0; r2 < 4; r2++) {
                int ig = mt * 128 + wm * 64 + mi * 16 + lg * 4 + r2;
                Cout[(size_t)ig * HID + jg] = acc[mi][ni][r2] + bb;
            }
        }
    }
}

// ---------------- fused flash attention: R2 datapath, 2 Q-blocks per wave (R5/R9 best) ----------------
__device__ __forceinline__ void stage_kv(
    const u16* __restrict__ Kg, const u16* __restrict__ Vg, int mt0,
    u16* Ksb, u16* Vsb, int kr0, int kc0, int kr1, int kc1, int w)
{
    gl2lds16(Kg + (size_t)(mt0 + kr0) * HD + kc0 * 8, Ksb + w * 512);
    gl2lds16(Kg + (size_t)(mt0 + kr1) * HD + kc1 * 8, Ksb + 2048 + w * 512);
    gl2lds16(Vg + (size_t)kr0 * SEQ + mt0 + kc0 * 8, Vsb + w * 512);
    gl2lds16(Vg + (size_t)kr1 * SEQ + mt0 + kc1 * 8, Vsb + 2048 + w * 512);
}

__global__ __launch_bounds__(256, 3) void attn_kernel(
    const u16* __restrict__ qtb, const u16* __restrict__ kb, const u16* __restrict__ vtb,
    const u16* __restrict__ ebb, u16* __restrict__ ob)
{
    __shared__ __align__(16) u16 Ks[2][64 * 64];
    __shared__ __align__(16) u16 Vs[2][64 * 64];
    __shared__ __align__(16) u16 Ps[8][16 * 64];   // 2 slabs per wave (qb0: w, qb1: 4+w)

    const int tid = threadIdx.x;
    const int l = tid & 63, w = tid >> 6;
    const int lr = l & 15, lg = l >> 4;

    // XCD-aware decode: 768 blocks = 8 xcd * (2 b * 12 h * 4 qt); h outer, qt inner.
    const int L = blockIdx.x;
    const int xcd = L & 7, s = L >> 3;            // s in [0,96)
    const int b = xcd * 2 + (s / 48);
    const int s2 = s % 48;
    const int h = s2 >> 2, qt = s2 & 3;

    const int bh = b * NH + h;
    const int qrow0 = qt * 128 + w * 16;          // qb0 rows; qb1 = qrow0 + 64

    const u16* Kg = kb + (size_t)bh * SEQ * HD;
    const u16* Vg = vtb + (size_t)bh * HD * SEQ;
    const u16* Eg0 = ebb + ((size_t)b * SEQ + qrow0 + lg * 4) * SEQ;
    const u16* Eg1 = Eg0 + (size_t)64 * SEQ;

    // staging chunk assignment (swizzled): p = row*8 + (c ^ (row&7))
    const int p0 = tid, p1 = tid + 256;
    const int kr0 = p0 >> 3, kc0 = (p0 & 7) ^ (kr0 & 7);
    const int kr1 = p1 >> 3, kc1 = (p1 & 7) ^ (kr1 & 7);

    stage_kv(Kg, Vg, 0, Ks[0], Vs[0], kr0, kc0, kr1, kc1, w);

    // Q fragments (A-layout) gathered from transposed Q [b,h,d,n]; two q-blocks
    const u16* Qg = qtb + (size_t)bh * HD * SEQ + qrow0 + lr;
    bf16x8 qA0, qA1, qB0, qB1;
#pragma unroll
    for (int j = 0; j < 8; j++) {
        qA0[j] = __builtin_bit_cast(__bf16, Qg[(size_t)(lg * 8 + j) * SEQ]);
        qA1[j] = __builtin_bit_cast(__bf16, Qg[(size_t)(lg * 8 + j + 32) * SEQ]);
        qB0[j] = __builtin_bit_cast(__bf16, Qg[(size_t)(lg * 8 + j) * SEQ + 64]);
        qB1[j] = __builtin_bit_cast(__bf16, Qg[(size_t)(lg * 8 + j + 32) * SEQ + 64]);
    }

    bf16x8 ones;
#pragma unroll
    for (int j = 0; j < 8; j++) ones[j] = __builtin_bit_cast(__bf16, (u16)0x3F80);

    f32x4 oacc0[4] = {}, oacc1[4] = {};
    f32x4 lacc0 = {}, lacc1 = {};
    float amax0[4] = {0.f, 0.f, 0.f, 0.f};
    float amax1[4] = {0.f, 0.f, 0.f, 0.f};
    u16* Pw0 = Ps[w];
    u16* Pw1 = Ps[4 + w];

    for (int t = 0; t < 8; t++) {
        const int cur = t & 1;
        const int mt0 = t * 64;
        __syncthreads();  // drains tile-t loads; prev tile's reads done

        // bias loads FIRST (vmcnt-ordered before the prefetch below)
        u16 bl0[4][4], bl1[4][4];
#pragma unroll
        for (int mi = 0; mi < 4; mi++)
#pragma unroll
            for (int r = 0; r < 4; r++) {
                bl0[mi][r] = Eg0[(size_t)r * SEQ + mt0 + mi * 16 + lr];
                bl1[mi][r] = Eg1[(size_t)r * SEQ + mt0 + mi * 16 + lr];
            }

        if (t < 7)
            stage_kv(Kg, Vg, mt0 + 64, Ks[cur ^ 1], Vs[cur ^ 1], kr0, kc0, kr1, kc1, w);

        // S = (Q*scale) K^T + bias (bias as MFMA C-init); P = exp(S), no max.
        // kf fragments read ONCE, feed both q-blocks.
        float sm0[4][4], sm1[4][4];
#pragma unroll
        for (int mi = 0; mi < 4; mi++) {
            const int row = mi * 16 + lr;
            bf16x8 kf0 = *(const bf16x8*)(Ks[cur] + row * 64 + ((lg ^ (row & 7)) * 8));
            bf16x8 kf1 = *(const bf16x8*)(Ks[cur] + row * 64 + (((4 + lg) ^ (row & 7)) * 8));
            f32x4 s0, s1;
#pragma unroll
            for (int r = 0; r < 4; r++) { s0[r] = bf2f(bl0[mi][r]); s1[r] = bf2f(bl1[mi][r]); }
            s0 = __builtin_amdgcn_mfma_f32_16x16x32_bf16(qA0, kf0, s0, 0, 0, 0);
            s0 = __builtin_amdgcn_mfma_f32_16x16x32_bf16(qA1, kf1, s0, 0, 0, 0);
            s1 = __builtin_amdgcn_mfma_f32_16x16x32_bf16(qB0, kf0, s1, 0, 0, 0);
            s1 = __builtin_amdgcn_mfma_f32_16x16x32_bf16(qB1, kf1, s1, 0, 0, 0);
#pragma unroll
            for (int r = 0; r < 4; r++) {
                float a = s0[r], c = s1[r];
                amax0[r] = fmaxf(amax0[r], fabsf(a));
                amax1[r] = fmaxf(amax1[r], fabsf(c));
                sm0[mi][r] = __expf(a);
                sm1[mi][r] = __expf(c);
            }
        }

        // P: C-layout -> per-wave swizzled LDS (two slabs) -> A-layout
#pragma unroll
        for (int mi = 0; mi < 4; mi++)
#pragma unroll
            for (int r = 0; r < 4; r++) {
                const int q = lg * 4 + r;
                const int chunk = mi * 2 + (lr >> 3);
                const int off = q * 64 + ((chunk ^ (q & 7)) * 8) + (lr & 7);
                Pw0[off] = f2bf(sm0[mi][r]);
                Pw1[off] = f2bf(sm1[mi][r]);
            }

        // PV: vf fragments read ONCE, feed both q-blocks.
#pragma unroll
        for (int ks = 0; ks < 2; ks++) {
            bf16x8 pf0 = *(const bf16x8*)(Pw0 + lr * 64 + (((ks * 4 + lg) ^ (lr & 7)) * 8));
            bf16x8 pf1 = *(const bf16x8*)(Pw1 + lr * 64 + (((ks * 4 + lg) ^ (lr & 7)) * 8));
#pragma unroll
            for (int di = 0; di < 4; di++) {
                const int row = di * 16 + lr;
                bf16x8 vf = *(const bf16x8*)(Vs[cur] + row * 64 + (((ks * 4 + lg) ^ (row & 7)) * 8));
                oacc0[di] = __builtin_amdgcn_mfma_f32_16x16x32_bf16(pf0, vf, oacc0[di], 0, 0, 0);
                oacc1[di] = __builtin_amdgcn_mfma_f32_16x16x32_bf16(pf1, vf, oacc1[di], 0, 0, 0);
            }
            lacc0 = __builtin_amdgcn_mfma_f32_16x16x32_bf16(pf0, ones, lacc0, 0, 0, 0);
            lacc1 = __builtin_amdgcn_mfma_f32_16x16x32_bf16(pf1, ones, lacc1, 0, 0, 0);
        }
    }

#pragma unroll
    for (int r = 0; r < 4; r++) {
        float am0 = amax0[r], am1 = amax1[r];
        am0 = fmaxf(am0, __shfl_xor(am0, 1));
        am0 = fmaxf(am0, __shfl_xor(am0, 2));
        am0 = fmaxf(am0, __shfl_xor(am0, 4));
        am0 = fmaxf(am0, __shfl_xor(am0, 8));
        am1 = fmaxf(am1, __shfl_xor(am1, 1));
        am1 = fmaxf(am1, __shfl_xor(am1, 2));
        am1 = fmaxf(am1, __shfl_xor(am1, 4));
        am1 = fmaxf(am1, __shfl_xor(am1, 8));
        float inv0 = (am0 > 0.f) ? (1.0f / lacc0[r]) : 0.0f;  // all-zero row -> 0 (ref: NaN->0)
        float inv1 = (am1 > 0.f) ? (1.0f / lacc1[r]) : 0.0f;
        int n0 = qrow0 + lg * 4 + r;
        u16* orow0 = ob + ((size_t)b * SEQ + n0) * HID + h * HD;
        u16* orow1 = ob + ((size_t)b * SEQ + n0 + 64) * HID + h * HD;
#pragma unroll
        for (int di = 0; di < 4; di++) {
            orow0[di * 16 + lr] = f2bf(oacc0[di][r] * inv0);
            orow1[di * 16 + lr] = f2bf(oacc1[di][r] * inv1);
        }
    }
}

// ---------------- launch ----------------
extern "C" void kernel_launch(void* const* d_in, const int* in_sizes, int n_in,
                              void* d_out, int out_size, void* d_ws, size_t ws_size,
                              hipStream_t stream) {
    (void)in_sizes; (void)n_in; (void)out_size; (void)ws_size;
    const float* x  = (const float*)d_in[0];
    const float* eb = (const float*)d_in[1];
    const float* Wq = (const float*)d_in[2];
    const float* Wk = (const float*)d_in[3];
    const float* Wv = (const float*)d_in[4];
    const float* bv = (const float*)d_in[5];
    const float* Wo = (const float*)d_in[6];
    const float* bo = (const float*)d_in[7];
    float* out = (float*)d_out;

    const int NX = BATCH * SEQ * HID;   // 6291456
    const int NW = HID * HID;           // 589824
    const int NE = BATCH * SEQ * SEQ;   // 4194304
    u16* ws   = (u16*)d_ws;
    u16* xb   = ws;                 // contiguous cvt region: [x | eb | wq | wk | wv | wo]
    u16* ebb  = xb + NX;
    u16* wqb  = ebb + NE;
    u16* wkb  = wqb + NW;
    u16* wvb  = wkb + NW;
    u16* wob  = wvb + NW;
    u16* qtb  = wob + NW;
    u16* kb   = qtb + NX;
    u16* vtb  = kb + NX;
    u16* obuf = vtb + NX;

    cvt_all<<<NXB + NEB + 4 * NWB, 256, 0, stream>>>(x, eb, Wq, Wk, Wv, Wo, ws);

    gemm_qkv<<<dim3(64, 6), 768, 0, stream>>>(xb, wqb, wkb, wvb, bv, qtb, kb, vtb);

    attn_kernel<<<768, 256, 0, stream>>>(qtb, kb, vtb, ebb, obuf);

    gemm_out<<<384, 256, 0, stream>>>(obuf, wob, bo, out);
}

// Round 11
// 191.666 us; speedup vs baseline: 1.1226x; 1.0310x over previous
//
#include <hip/hip_runtime.h>
#include <stdint.h>

typedef unsigned short u16;
typedef unsigned int u32;
typedef __bf16 bf16x8 __attribute__((ext_vector_type(8)));
typedef float f32x4 __attribute__((ext_vector_type(4)));

#define NH 12
#define HD 64
#define SEQ 512
#define BATCH 16
#define HID 768
#define SCALE_Q 0.03608439182435161f  // 768^-0.5

__device__ __forceinline__ u16 f2bf(float f) {
    u32 u = __builtin_bit_cast(u32, f);
    u32 r = (u + 0x7FFFu + ((u >> 16) & 1u)) >> 16;
    return (u16)r;
}
__device__ __forceinline__ float bf2f(u16 h) {
    return __builtin_bit_cast(float, (u32)h << 16);
}

// async global -> LDS, 16B per lane; lds dest = wave-uniform base + lane*16
__device__ __forceinline__ void gl2lds16(const u16* g, u16* lds_base) {
    __builtin_amdgcn_global_load_lds(
        (const __attribute__((address_space(1))) u32*)g,
        (__attribute__((address_space(3))) u32*)lds_base, 16, 0, 0);
}

// ---------------- fused fp32 -> bf16 convert (all 6 tensors, one launch) ----------------
#define NXB 6144   // NX/1024
#define NEB 4096   // NE/1024
#define NWB 576    // NW/1024
__global__ void cvt_all(const float* __restrict__ x, const float* __restrict__ eb,
                        const float* __restrict__ w0, const float* __restrict__ w1,
                        const float* __restrict__ w2, const float* __restrict__ w3,
                        u16* __restrict__ dst) {
    int b = blockIdx.x;
    const float* s; int sb;
    if (b < NXB) { s = x; sb = 0; }
    else if (b < NXB + NEB) { s = eb; sb = NXB; }
    else if (b < NXB + NEB + NWB) { s = w0; sb = NXB + NEB; }
    else if (b < NXB + NEB + 2 * NWB) { s = w1; sb = NXB + NEB + NWB; }
    else if (b < NXB + NEB + 3 * NWB) { s = w2; sb = NXB + NEB + 2 * NWB; }
    else { s = w3; sb = NXB + NEB + 3 * NWB; }
    int li = (b - sb) * 1024 + threadIdx.x * 4;
    float4 v = *(const float4*)(s + li);
    ushort4 o;
    o.x = f2bf(v.x); o.y = f2bf(v.y); o.z = f2bf(v.z); o.w = f2bf(v.w);
    *(ushort4*)(dst + (size_t)b * 1024 + threadIdx.x * 4) = o;
}

// ---------------- NT GEMM mainloop: 3-buffer ring, prefetch distance 2, counted vmcnt ----------------
// (R1 verbatim — measured 54-58 us for gemm_qkv; at the m97-structure ceiling for this shape)
__device__ __forceinline__ void stage_gemm(
    const u16* __restrict__ Ag, const u16* __restrict__ Bg, int k0,
    u16* As, u16* Bs, int r0, int q0, int r1, int q1, int w)
{
    gl2lds16(Ag + (size_t)r0 * HID + k0 + q0, As + w * 512);
    gl2lds16(Ag + (size_t)r1 * HID + k0 + q1, As + 2048 + w * 512);
    gl2lds16(Bg + (size_t)r0 * HID + k0 + q0, Bs + w * 512);
    gl2lds16(Bg + (size_t)r1 * HID + k0 + q1, Bs + 2048 + w * 512);
}

__device__ __forceinline__ void gemm_mainloop(
    const u16* __restrict__ Ag, const u16* __restrict__ Bg,
    u16 (*As)[128 * 32], u16 (*Bs)[128 * 32], f32x4 (&acc)[4][4])
{
    const int tid = threadIdx.x;
    const int l = tid & 63, w = tid >> 6;
    const int wm = w & 1, wn = w >> 1;
    const int lr = l & 15, lg = l >> 4;

    const int c0 = tid, c1 = tid + 256;
    const int r0 = c0 >> 2, q0 = (((c0 & 3) ^ ((r0 >> 1) & 3)) * 8);
    const int r1 = c1 >> 2, q1 = (((c1 & 3) ^ ((r1 >> 1) & 3)) * 8);

    const int sA = (lg ^ ((lr >> 1) & 3)) * 8;

    stage_gemm(Ag, Bg, 0, As[0], Bs[0], r0, q0, r1, q1, w);
    stage_gemm(Ag, Bg, 32, As[1], Bs[1], r0, q0, r1, q1, w);

    int cur = 0;
    for (int i = 0; i < 24; i++) {
        if (i < 23)
            asm volatile("s_waitcnt vmcnt(4) lgkmcnt(0)" ::: "memory");
        else
            asm volatile("s_waitcnt vmcnt(0) lgkmcnt(0)" ::: "memory");
        __builtin_amdgcn_s_barrier();
        __builtin_amdgcn_sched_barrier(0);

        int nxt = cur + 2; if (nxt >= 3) nxt -= 3;
        if (i < 22)
            stage_gemm(Ag, Bg, (i + 2) * 32, As[nxt], Bs[nxt], r0, q0, r1, q1, w);

        bf16x8 af[4], bfr[4];
#pragma unroll
        for (int mi = 0; mi < 4; mi++)
            af[mi] = *(const bf16x8*)(As[cur] + (wm * 64 + mi * 16 + lr) * 32 + sA);
#pragma unroll
        for (int ni = 0; ni < 4; ni++)
            bfr[ni] = *(const bf16x8*)(Bs[cur] + (wn * 64 + ni * 16 + lr) * 32 + sA);
#pragma unroll
        for (int mi = 0; mi < 4; mi++)
#pragma unroll
            for (int ni = 0; ni < 4; ni++)
                acc[mi][ni] = __builtin_amdgcn_mfma_f32_16x16x32_bf16(af[mi], bfr[ni], acc[mi][ni], 0, 0, 0);

        cur += 1; if (cur >= 3) cur -= 3;
    }
}

// ---------------- fused QKV GEMM: R1 mainloop + COALESCED Q/V epilogue (LDS transpose) ----------------
// Q/V stores were 8B per lane at 1024B stride (64 cache lines per wave-store). Now: acc ->
// swizzled LDS [d=128][n=128] bf16 tile (reuses the 48KB staging LDS) -> 16B uint4 stores where
// each 16-lane group writes a 256B contiguous row segment. K epilogue (natural layout) unchanged.
__global__ __launch_bounds__(256, 3) void gemm_qkv(
    const u16* __restrict__ xb, const u16* __restrict__ wq,
    const u16* __restrict__ wk, const u16* __restrict__ wv,
    const float* __restrict__ bv,
    u16* __restrict__ qtb, u16* __restrict__ kb, u16* __restrict__ vtb)
{
    __shared__ __align__(16) u16 SH[6 * 4096];   // 48 KB: As = SH[0..3), Bs = SH[3..6) tiles
    u16 (*As)[128 * 32] = reinterpret_cast<u16 (*)[128 * 32]>(SH);
    u16 (*Bs)[128 * 32] = reinterpret_cast<u16 (*)[128 * 32]>(SH + 3 * 4096);
    const int tid = threadIdx.x;
    const int l = tid & 63, w = tid >> 6;
    const int wm = w & 1, wn = w >> 1;
    const int lr = l & 15, lg = l >> 4;
    const int mt = blockIdx.x, nt = blockIdx.y, z = blockIdx.z;

    const u16* Bw = (z == 0) ? wq : (z == 1) ? wk : wv;
    const u16* Ag = xb + (size_t)(mt * 128) * HID;
    const u16* Bg = Bw + (size_t)(nt * 128) * HID;

    f32x4 acc[4][4] = {};
    gemm_mainloop(Ag, Bg, As, Bs, acc);

    if (z == 1) {
        // K: [b,h,n,d] — natural C layout, 32B segments per 16-lane group (unchanged)
#pragma unroll
        for (int mi = 0; mi < 4; mi++) {
#pragma unroll
            for (int ni = 0; ni < 4; ni++) {
                const int jg = nt * 128 + wn * 64 + ni * 16 + lr;
                const int h = jg >> 6, d = jg & 63;
                const int i0 = mt * 128 + wm * 64 + mi * 16 + lg * 4;
                const int b = i0 >> 9, n0 = i0 & 511;
#pragma unroll
                for (int r2 = 0; r2 < 4; r2++)
                    kb[((size_t)(b * NH + h) * SEQ + n0 + r2) * HD + d] = f2bf(acc[mi][ni][r2]);
            }
        }
    } else {
        // Q/V: [b,h,d,n] — transpose through LDS for coalesced stores
        const float sc = (z == 0) ? SCALE_Q : 1.0f;
        __syncthreads();                 // mainloop LDS reads complete before reuse
        u16* T = SH;                     // 128 cols(d) x 128 rows(n) bf16 = 32 KB
#pragma unroll
        for (int mi = 0; mi < 4; mi++) {
#pragma unroll
            for (int ni = 0; ni < 4; ni++) {
                const int col = wn * 64 + ni * 16 + lr;          // d-local
                const int rowb = wm * 64 + mi * 16 + lg * 4;     // n-local
                float bb = (z == 2) ? bv[nt * 128 + col] : 0.0f;
                ushort4 pk;
                pk.x = f2bf(fmaf(acc[mi][ni][0], sc, bb));
                pk.y = f2bf(fmaf(acc[mi][ni][1], sc, bb));
                pk.z = f2bf(fmaf(acc[mi][ni][2], sc, bb));
                pk.w = f2bf(fmaf(acc[mi][ni][3], sc, bb));
                // swizzle: XOR n-index with (col&7)<<4 (16-elem granules) to spread banks
                *(ushort4*)(T + col * 128 + (rowb ^ ((col & 7) << 4))) = pk;
            }
        }
        __syncthreads();
        const int b = mt >> 2, n0b = (mt & 3) * 128;
        u16* O = (z == 0) ? qtb : vtb;
#pragma unroll
        for (int p = 0; p < 8; p++) {
            const int idx = p * 256 + tid;
            const int col = idx >> 4, c = idx & 15;              // 16 lanes cover one 256B row seg
            uint4 v = *(const uint4*)(T + col * 128 + ((c * 8) ^ ((col & 7) << 4)));
            const int jg = nt * 128 + col;
            const int h = jg >> 6, d = jg & 63;
            *(uint4*)(O + ((size_t)(b * NH + h) * HD + d) * SEQ + n0b + c * 8) = v;
        }
    }
}

// ---------------- output GEMM: fp32 out + bias (R2 XCD-chunked remap) ----------------
__global__ __launch_bounds__(256, 3) void gemm_out(
    const u16* __restrict__ A, const u16* __restrict__ wo,
    const float* __restrict__ bo, float* __restrict__ Cout)
{
    __shared__ __align__(16) u16 As[3][128 * 32];
    __shared__ __align__(16) u16 Bs[3][128 * 32];
    const int tid = threadIdx.x;
    const int l = tid & 63, w = tid >> 6;
    const int wm = w & 1, wn = w >> 1;
    const int lr = l & 15, lg = l >> 4;

    const int L = blockIdx.x;
    const int xcd = L & 7, s = L >> 3;
    const int nt = s >> 3;
    const int mt = xcd * 8 + (s & 7);

    const u16* Ag = A + (size_t)(mt * 128) * HID;
    const u16* Bg = wo + (size_t)(nt * 128) * HID;

    f32x4 acc[4][4] = {};
    gemm_mainloop(Ag, Bg, As, Bs, acc);

#pragma unroll
    for (int mi = 0; mi < 4; mi++) {
#pragma unroll
        for (int ni = 0; ni < 4; ni++) {
            const int jg = nt * 128 + wn * 64 + ni * 16 + lr;
            float bb = bo[jg];
#pragma unroll
            for (int r2 = 0; r2 < 4; r2++) {
                int ig = mt * 128 + wm * 64 + mi * 16 + lg * 4 + r2;
                Cout[(size_t)ig * HID + jg] = acc[mi][ni][r2] + bb;
            }
        }
    }
}

// ---------------- fused flash attention: R2 datapath, 2 Q-blocks per wave (R5/R9 best) ----------------
__device__ __forceinline__ void stage_kv(
    const u16* __restrict__ Kg, const u16* __restrict__ Vg, int mt0,
    u16* Ksb, u16* Vsb, int kr0, int kc0, int kr1, int kc1, int w)
{
    gl2lds16(Kg + (size_t)(mt0 + kr0) * HD + kc0 * 8, Ksb + w * 512);
    gl2lds16(Kg + (size_t)(mt0 + kr1) * HD + kc1 * 8, Ksb + 2048 + w * 512);
    gl2lds16(Vg + (size_t)kr0 * SEQ + mt0 + kc0 * 8, Vsb + w * 512);
    gl2lds16(Vg + (size_t)kr1 * SEQ + mt0 + kc1 * 8, Vsb + 2048 + w * 512);
}

__global__ __launch_bounds__(256, 3) void attn_kernel(
    const u16* __restrict__ qtb, const u16* __restrict__ kb, const u16* __restrict__ vtb,
    const u16* __restrict__ ebb, u16* __restrict__ ob)
{
    __shared__ __align__(16) u16 Ks[2][64 * 64];
    __shared__ __align__(16) u16 Vs[2][64 * 64];
    __shared__ __align__(16) u16 Ps[8][16 * 64];   // 2 slabs per wave (qb0: w, qb1: 4+w)

    const int tid = threadIdx.x;
    const int l = tid & 63, w = tid >> 6;
    const int lr = l & 15, lg = l >> 4;

    // XCD-aware decode: 768 blocks = 8 xcd * (2 b * 12 h * 4 qt); h outer, qt inner.
    const int L = blockIdx.x;
    const int xcd = L & 7, s = L >> 3;            // s in [0,96)
    const int b = xcd * 2 + (s / 48);
    const int s2 = s % 48;
    const int h = s2 >> 2, qt = s2 & 3;

    const int bh = b * NH + h;
    const int qrow0 = qt * 128 + w * 16;          // qb0 rows; qb1 = qrow0 + 64

    const u16* Kg = kb + (size_t)bh * SEQ * HD;
    const u16* Vg = vtb + (size_t)bh * HD * SEQ;
    const u16* Eg0 = ebb + ((size_t)b * SEQ + qrow0 + lg * 4) * SEQ;
    const u16* Eg1 = Eg0 + (size_t)64 * SEQ;

    // staging chunk assignment (swizzled): p = row*8 + (c ^ (row&7))
    const int p0 = tid, p1 = tid + 256;
    const int kr0 = p0 >> 3, kc0 = (p0 & 7) ^ (kr0 & 7);
    const int kr1 = p1 >> 3, kc1 = (p1 & 7) ^ (kr1 & 7);

    stage_kv(Kg, Vg, 0, Ks[0], Vs[0], kr0, kc0, kr1, kc1, w);

    // Q fragments (A-layout) gathered from transposed Q [b,h,d,n]; two q-blocks
    const u16* Qg = qtb + (size_t)bh * HD * SEQ + qrow0 + lr;
    bf16x8 qA0, qA1, qB0, qB1;
#pragma unroll
    for (int j = 0; j < 8; j++) {
        qA0[j] = __builtin_bit_cast(__bf16, Qg[(size_t)(lg * 8 + j) * SEQ]);
        qA1[j] = __builtin_bit_cast(__bf16, Qg[(size_t)(lg * 8 + j + 32) * SEQ]);
        qB0[j] = __builtin_bit_cast(__bf16, Qg[(size_t)(lg * 8 + j) * SEQ + 64]);
        qB1[j] = __builtin_bit_cast(__bf16, Qg[(size_t)(lg * 8 + j + 32) * SEQ + 64]);
    }

    bf16x8 ones;
#pragma unroll
    for (int j = 0; j < 8; j++) ones[j] = __builtin_bit_cast(__bf16, (u16)0x3F80);

    f32x4 oacc0[4] = {}, oacc1[4] = {};
    f32x4 lacc0 = {}, lacc1 = {};
    float amax0[4] = {0.f, 0.f, 0.f, 0.f};
    float amax1[4] = {0.f, 0.f, 0.f, 0.f};
    u16* Pw0 = Ps[w];
    u16* Pw1 = Ps[4 + w];

    for (int t = 0; t < 8; t++) {
        const int cur = t & 1;
        const int mt0 = t * 64;
        __syncthreads();  // drains tile-t loads; prev tile's reads done

        // bias loads FIRST (vmcnt-ordered before the prefetch below)
        u16 bl0[4][4], bl1[4][4];
#pragma unroll
        for (int mi = 0; mi < 4; mi++)
#pragma unroll
            for (int r = 0; r < 4; r++) {
                bl0[mi][r] = Eg0[(size_t)r * SEQ + mt0 + mi * 16 + lr];
                bl1[mi][r] = Eg1[(size_t)r * SEQ + mt0 + mi * 16 + lr];
            }

        if (t < 7)
            stage_kv(Kg, Vg, mt0 + 64, Ks[cur ^ 1], Vs[cur ^ 1], kr0, kc0, kr1, kc1, w);

        // S = (Q*scale) K^T + bias (bias as MFMA C-init); P = exp(S), no max.
        // kf fragments read ONCE, feed both q-blocks.
        float sm0[4][4], sm1[4][4];
#pragma unroll
        for (int mi = 0; mi < 4; mi++) {
            const int row = mi * 16 + lr;
            bf16x8 kf0 = *(const bf16x8*)(Ks[cur] + row * 64 + ((lg ^ (row & 7)) * 8));
            bf16x8 kf1 = *(const bf16x8*)(Ks[cur] + row * 64 + (((4 + lg) ^ (row & 7)) * 8));
            f32x4 s0, s1;
#pragma unroll
            for (int r = 0; r < 4; r++) { s0[r] = bf2f(bl0[mi][r]); s1[r] = bf2f(bl1[mi][r]); }
            s0 = __builtin_amdgcn_mfma_f32_16x16x32_bf16(qA0, kf0, s0, 0, 0, 0);
            s0 = __builtin_amdgcn_mfma_f32_16x16x32_bf16(qA1, kf1, s0, 0, 0, 0);
            s1 = __builtin_amdgcn_mfma_f32_16x16x32_bf16(qB0, kf0, s1, 0, 0, 0);
            s1 = __builtin_amdgcn_mfma_f32_16x16x32_bf16(qB1, kf1, s1, 0, 0, 0);
#pragma unroll
            for (int r = 0; r < 4; r++) {
                float a = s0[r], c = s1[r];
                amax0[r] = fmaxf(amax0[r], fabsf(a));
                amax1[r] = fmaxf(amax1[r], fabsf(c));
                sm0[mi][r] = __expf(a);
                sm1[mi][r] = __expf(c);
            }
        }

        // P: C-layout -> per-wave swizzled LDS (two slabs) -> A-layout
#pragma unroll
        for (int mi = 0; mi < 4; mi++)
#pragma unroll
            for (int r = 0; r < 4; r++) {
                const int q = lg * 4 + r;
                const int chunk = mi * 2 + (lr >> 3);
                const int off = q * 64 + ((chunk ^ (q & 7)) * 8) + (lr & 7);
                Pw0[off] = f2bf(sm0[mi][r]);
                Pw1[off] = f2bf(sm1[mi][r]);
            }

        // PV: vf fragments read ONCE, feed both q-blocks.
#pragma unroll
        for (int ks = 0; ks < 2; ks++) {
            bf16x8 pf0 = *(const bf16x8*)(Pw0 + lr * 64 + (((ks * 4 + lg) ^ (lr & 7)) * 8));
            bf16x8 pf1 = *(const bf16x8*)(Pw1 + lr * 64 + (((ks * 4 + lg) ^ (lr & 7)) * 8));
#pragma unroll
            for (int di = 0; di < 4; di++) {
                const int row = di * 16 + lr;
                bf16x8 vf = *(const bf16x8*)(Vs[cur] + row * 64 + (((ks * 4 + lg) ^ (row & 7)) * 8));
                oacc0[di] = __builtin_amdgcn_mfma_f32_16x16x32_bf16(pf0, vf, oacc0[di], 0, 0, 0);
                oacc1[di] = __builtin_amdgcn_mfma_f32_16x16x32_bf16(pf1, vf, oacc1[di], 0, 0, 0);
            }
            lacc0 = __builtin_amdgcn_mfma_f32_16x16x32_bf16(pf0, ones, lacc0, 0, 0, 0);
            lacc1 = __builtin_amdgcn_mfma_f32_16x16x32_bf16(pf1, ones, lacc1, 0, 0, 0);
        }
    }

#pragma unroll
    for (int r = 0; r < 4; r++) {
        float am0 = amax0[r], am1 = amax1[r];
        am0 = fmaxf(am0, __shfl_xor(am0, 1));
        am0 = fmaxf(am0, __shfl_xor(am0, 2));
        am0 = fmaxf(am0, __shfl_xor(am0, 4));
        am0 = fmaxf(am0, __shfl_xor(am0, 8));
        am1 = fmaxf(am1, __shfl_xor(am1, 1));
        am1 = fmaxf(am1, __shfl_xor(am1, 2));
        am1 = fmaxf(am1, __shfl_xor(am1, 4));
        am1 = fmaxf(am1, __shfl_xor(am1, 8));
        float inv0 = (am0 > 0.f) ? (1.0f / lacc0[r]) : 0.0f;  // all-zero row -> 0 (ref: NaN->0)
        float inv1 = (am1 > 0.f) ? (1.0f / lacc1[r]) : 0.0f;
        int n0 = qrow0 + lg * 4 + r;
        u16* orow0 = ob + ((size_t)b * SEQ + n0) * HID + h * HD;
        u16* orow1 = ob + ((size_t)b * SEQ + n0 + 64) * HID + h * HD;
#pragma unroll
        for (int di = 0; di < 4; di++) {
            orow0[di * 16 + lr] = f2bf(oacc0[di][r] * inv0);
            orow1[di * 16 + lr] = f2bf(oacc1[di][r] * inv1);
        }
    }
}

// ---------------- launch ----------------
extern "C" void kernel_launch(void* const* d_in, const int* in_sizes, int n_in,
                              void* d_out, int out_size, void* d_ws, size_t ws_size,
                              hipStream_t stream) {
    (void)in_sizes; (void)n_in; (void)out_size; (void)ws_size;
    const float* x  = (const float*)d_in[0];
    const float* eb = (const float*)d_in[1];
    const float* Wq = (const float*)d_in[2];
    const float* Wk = (const float*)d_in[3];
    const float* Wv = (const float*)d_in[4];
    const float* bv = (const float*)d_in[5];
    const float* Wo = (const float*)d_in[6];
    const float* bo = (const float*)d_in[7];
    float* out = (float*)d_out;

    const int NX = BATCH * SEQ * HID;   // 6291456
    const int NW = HID * HID;           // 589824
    const int NE = BATCH * SEQ * SEQ;   // 4194304
    u16* ws   = (u16*)d_ws;
    u16* xb   = ws;                 // contiguous cvt region: [x | eb | wq | wk | wv | wo]
    u16* ebb  = xb + NX;
    u16* wqb  = ebb + NE;
    u16* wkb  = wqb + NW;
    u16* wvb  = wkb + NW;
    u16* wob  = wvb + NW;
    u16* qtb  = wob + NW;
    u16* kb   = qtb + NX;
    u16* vtb  = kb + NX;
    u16* obuf = vtb + NX;

    cvt_all<<<NXB + NEB + 4 * NWB, 256, 0, stream>>>(x, eb, Wq, Wk, Wv, Wo, ws);

    gemm_qkv<<<dim3(64, 6, 3), 256, 0, stream>>>(xb, wqb, wkb, wvb, bv, qtb, kb, vtb);

    attn_kernel<<<768, 256, 0, stream>>>(qtb, kb, vtb, ebb, obuf);

    gemm_out<<<384, 256, 0, stream>>>(obuf, wob, bo, out);
}